// Round 1
// baseline (3580.655 us; speedup 1.0000x reference)
//
#include <hip/hip_runtime.h>
#include <cstdint>
#include <cstddef>

#define D_MODEL 512
#define NHEADS  8
#define EDIM    64
#define BATCH   8
#define LSEQ    4096

// ======================= GEMM: Y = X @ W (+bias) ===========================
// X: Mrows x 512 row-major, W: 512 x 512 row-major, Y: Mrows x 512.
// 64x64 tile per block, BK=16, 256 threads, 4x4 micro-tile per thread.
__global__ __launch_bounds__(256) void gemm512(
    const float* __restrict__ X, const float* __restrict__ W,
    const float* __restrict__ bias, float* __restrict__ Y) {
  __shared__ float As[16][68];   // [k][m], padded
  __shared__ float Bs[16][68];   // [k][n], padded (68 keeps float4 16B-aligned)
  const int tid = threadIdx.x;
  const int bm = blockIdx.y * 64;
  const int bn = blockIdx.x * 64;
  const int tx = tid & 15, ty = tid >> 4;
  const int m0 = ty * 4, n0 = tx * 4;
  const int am = tid >> 2, ak4 = (tid & 3) * 4;       // A-load mapping
  const int bk = tid >> 4, bn4 = (tid & 15) * 4;      // B-load mapping
  const float* Xp = X + (size_t)(bm + am) * D_MODEL + ak4;
  const float* Wp = W + (size_t)bk * D_MODEL + bn + bn4;
  float acc[4][4] = {};
  for (int k0 = 0; k0 < D_MODEL; k0 += 16) {
    float4 a  = *(const float4*)(Xp + k0);
    float4 bv = *(const float4*)(Wp + (size_t)k0 * D_MODEL);
    As[ak4 + 0][am] = a.x; As[ak4 + 1][am] = a.y;
    As[ak4 + 2][am] = a.z; As[ak4 + 3][am] = a.w;
    *(float4*)&Bs[bk][bn4] = bv;
    __syncthreads();
#pragma unroll
    for (int k = 0; k < 16; ++k) {
      float av[4], bw[4];
#pragma unroll
      for (int i = 0; i < 4; ++i) av[i] = As[k][m0 + i];
#pragma unroll
      for (int j = 0; j < 4; ++j) bw[j] = Bs[k][n0 + j];
#pragma unroll
      for (int i = 0; i < 4; ++i)
#pragma unroll
        for (int j = 0; j < 4; ++j) acc[i][j] += av[i] * bw[j];
    }
    __syncthreads();
  }
#pragma unroll
  for (int i = 0; i < 4; ++i) {
    float* yp = Y + (size_t)(bm + m0 + i) * D_MODEL + bn + n0;
#pragma unroll
    for (int j = 0; j < 4; ++j) {
      float bb = bias ? bias[bn + n0 + j] : 0.0f;
      yp[j] = acc[i][j] + bb;
    }
  }
}

// ================= QK_sample -> M = max - mean per (b,h,q) =================
// One wave (64 lanes) per row; lane = e dim. M layout: M[(b*H+h)*L + q].
__global__ __launch_bounds__(256) void qk_sample_M(
    const float* __restrict__ Q, const float* __restrict__ K,
    const int* __restrict__ sidx, float* __restrict__ M, int S) {
  int w = blockIdx.x * (blockDim.x >> 6) + (threadIdx.x >> 6);
  int lane = threadIdx.x & 63;
  int q = w & (LSEQ - 1);
  int bh = w >> 12;
  int h = bh & (NHEADS - 1);
  int b = bh >> 3;
  const float* Qrow = Q + ((size_t)b * LSEQ + q) * D_MODEL + h * EDIM;
  float qv = Qrow[lane];
  float mx = -3.4e38f, sum = 0.0f;
  for (int j = 0; j < S; ++j) {
    int kk = sidx[q * S + j];
    float kv = K[((size_t)b * LSEQ + kk) * D_MODEL + h * EDIM + lane];
    float p = qv * kv;
#pragma unroll
    for (int o = 32; o > 0; o >>= 1) p += __shfl_xor(p, o, 64);
    mx = fmaxf(mx, p);
    sum += p;
  }
  if (lane == 0) M[w] = mx - sum / (float)S;
}

// ===================== top-U indices per (b,h) =============================
__global__ __launch_bounds__(256) void topk_kernel(
    const float* __restrict__ M, int* __restrict__ Mtop, int U) {
  __shared__ float vals[LSEQ];
  __shared__ float rmax[256];
  __shared__ int ridx[256];
  int bh = blockIdx.x;
  int t = threadIdx.x;
  for (int i = t; i < LSEQ; i += 256) vals[i] = M[(size_t)bh * LSEQ + i];
  __syncthreads();
  for (int it = 0; it < U; ++it) {
    float best = -3.4e38f; int bi = -1;
    for (int i = t; i < LSEQ; i += 256) {
      float v = vals[i];
      if (v > best) { best = v; bi = i; }
    }
    rmax[t] = best; ridx[t] = bi;
    __syncthreads();
    for (int s = 128; s > 0; s >>= 1) {
      if (t < s) {
        if (rmax[t + s] > rmax[t]) { rmax[t] = rmax[t + s]; ridx[t] = ridx[t + s]; }
      }
      __syncthreads();
    }
    if (t == 0) {
      Mtop[(size_t)bh * U + it] = ridx[0];
      vals[ridx[0]] = -3.4e38f;
    }
    __syncthreads();
  }
}

// ============== full attention for the top-U query rows ====================
// One block per (bh, u). scores for 4096 keys in LDS, softmax, ctx accumulate.
__global__ __launch_bounds__(256) void attn_rows(
    const float* __restrict__ Q, const float* __restrict__ K,
    const float* __restrict__ V, const int* __restrict__ Mtop,
    float* __restrict__ ctxTop, int U) {
  __shared__ float sc[LSEQ];
  __shared__ float wred[4];
  __shared__ float part[4][EDIM];
  int blk = blockIdx.x;
  int u = blk % U, bh = blk / U;
  int h = bh & (NHEADS - 1), b = bh >> 3;
  int q = Mtop[(size_t)bh * U + u];
  int t = threadIdx.x;
  int wave = t >> 6, lane = t & 63;
  float qv = Q[((size_t)b * LSEQ + q) * D_MODEL + h * EDIM + lane];
  const float scale = 0.125f;   // 1/sqrt(64)
  // scores
  for (int k = wave; k < LSEQ; k += 4) {
    float kv = K[((size_t)b * LSEQ + k) * D_MODEL + h * EDIM + lane];
    float p = qv * kv;
#pragma unroll
    for (int o = 32; o > 0; o >>= 1) p += __shfl_xor(p, o, 64);
    if (lane == 0) sc[k] = p * scale;
  }
  __syncthreads();
  // softmax max
  float mx = -3.4e38f;
  for (int i = t; i < LSEQ; i += 256) mx = fmaxf(mx, sc[i]);
#pragma unroll
  for (int o = 32; o > 0; o >>= 1) mx = fmaxf(mx, __shfl_xor(mx, o, 64));
  if (lane == 0) wred[wave] = mx;
  __syncthreads();
  mx = fmaxf(fmaxf(wred[0], wred[1]), fmaxf(wred[2], wred[3]));
  __syncthreads();
  // exp + sum
  float ssum = 0.0f;
  for (int i = t; i < LSEQ; i += 256) {
    float e = expf(sc[i] - mx);
    sc[i] = e;
    ssum += e;
  }
#pragma unroll
  for (int o = 32; o > 0; o >>= 1) ssum += __shfl_xor(ssum, o, 64);
  if (lane == 0) wred[wave] = ssum;
  __syncthreads();
  ssum = wred[0] + wred[1] + wred[2] + wred[3];
  float inv = 1.0f / ssum;
  // ctx accumulate: lane = e dim, wave strides keys
  float acc = 0.0f;
  for (int k = wave; k < LSEQ; k += 4) {
    acc += sc[k] * V[((size_t)b * LSEQ + k) * D_MODEL + h * EDIM + lane];
  }
  part[wave][lane] = acc * inv;
  __syncthreads();
  if (wave == 0) {
    float r = part[0][lane] + part[1][lane] + part[2][lane] + part[3][lane];
    ctxTop[((size_t)bh * U + u) * EDIM + lane] = r;
  }
}

// ====================== V.mean over keys per (b,h) =========================
__global__ __launch_bounds__(256) void vmean_kernel(
    const float* __restrict__ V, float* __restrict__ Vm) {
  __shared__ float part[4][EDIM];
  int bh = blockIdx.x;
  int h = bh & (NHEADS - 1), b = bh >> 3;
  int t = threadIdx.x;
  int e = t & 63, c = t >> 6;
  float s = 0.0f;
  for (int k = c * (LSEQ / 4); k < (c + 1) * (LSEQ / 4); ++k)
    s += V[((size_t)b * LSEQ + k) * D_MODEL + h * EDIM + e];
  part[c][e] = s;
  __syncthreads();
  if (c == 0)
    Vm[(size_t)bh * EDIM + e] =
        (part[0][e] + part[1][e] + part[2][e] + part[3][e]) * (1.0f / (float)LSEQ);
}

// ============ base_out[b] = concat_h(Vmean[b,h]) @ W_out + b_out ===========
__global__ __launch_bounds__(256) void base_out_kernel(
    const float* __restrict__ Vm, const float* __restrict__ Wout,
    const float* __restrict__ bout, float* __restrict__ base) {
  __shared__ float cb[D_MODEL];
  int b = blockIdx.x;
  int t = threadIdx.x;
  for (int d = t; d < D_MODEL; d += 256) cb[d] = Vm[(size_t)b * D_MODEL + d];
  __syncthreads();
  for (int n = t; n < D_MODEL; n += 256) {
    float s = bout[n];
    for (int d = 0; d < D_MODEL; ++d) s += cb[d] * Wout[(size_t)d * D_MODEL + n];
    base[(size_t)b * D_MODEL + n] = s;
  }
}

// ================== broadcast base row into all output rows ================
__global__ __launch_bounds__(256) void fill_out(
    const float* __restrict__ base, float* __restrict__ out) {
  size_t i = (size_t)blockIdx.x * 256 + threadIdx.x;  // float4 index
  int n4 = (int)(i & 127);        // 512/4 per row
  size_t bq = i >> 7;
  int b = (int)(bq >> 12);        // /4096
  float4 v = ((const float4*)base)[(size_t)b * 128 + n4];
  ((float4*)out)[i] = v;
}

// ====== add (ctxTop - Vmean) @ W_out[h-slice] into the top rows ============
__global__ __launch_bounds__(256) void delta_out(
    const float* __restrict__ ctxTop, const float* __restrict__ Vm,
    const int* __restrict__ Mtop, const float* __restrict__ Wout,
    float* __restrict__ out, int U) {
  __shared__ float dlt[EDIM];
  int blk = blockIdx.x;
  int u = blk % U, bh = blk / U;
  int h = bh & (NHEADS - 1), b = bh >> 3;
  int q = Mtop[(size_t)bh * U + u];
  int t = threadIdx.x;
  if (t < EDIM)
    dlt[t] = ctxTop[((size_t)bh * U + u) * EDIM + t] - Vm[(size_t)bh * EDIM + t];
  __syncthreads();
  float* orow = out + ((size_t)b * LSEQ + q) * D_MODEL;
  for (int n = t; n < D_MODEL; n += 256) {
    float s = 0.0f;
#pragma unroll
    for (int e = 0; e < EDIM; ++e) s += dlt[e] * Wout[(size_t)(h * EDIM + e) * D_MODEL + n];
    atomicAdd(&orow[n], s);
  }
}

// ===========================================================================
extern "C" void kernel_launch(void* const* d_in, const int* in_sizes, int n_in,
                              void* d_out, int out_size, void* d_ws, size_t ws_size,
                              hipStream_t stream) {
  const float* query  = (const float*)d_in[0];
  const float* key_in = (const float*)d_in[1];
  const float* value  = (const float*)d_in[2];
  const float* W_Q    = (const float*)d_in[3];
  const float* W_K    = (const float*)d_in[4];
  const float* W_V    = (const float*)d_in[5];
  const float* W_out  = (const float*)d_in[6];
  const float* b_out  = (const float*)d_in[7];
  const int*   sidx   = (const int*)d_in[8];
  float* out = (float*)d_out;

  const int S = in_sizes[8] / LSEQ;   // 41
  const int U = S;                    // same formula since L_Q == L_K

  char* ws = (char*)d_ws;
  float* Q      = (float*)(ws);                       // 64 MB
  float* K      = (float*)(ws + 67108864);            // 64 MB
  float* V      = (float*)(ws + 134217728);           // 64 MB
  float* M      = (float*)(ws + 201326592);           // 1 MB
  int*   Mtop   = (int*)  (ws + 202375168);           // 16 KB
  float* ctxTop = (float*)(ws + 202391552);           // ~672 KB (padded 1 MB)
  float* Vm     = (float*)(ws + 203440128);           // 16 KB
  float* baseO  = (float*)(ws + 203456512);           // 16 KB

  dim3 gblk(D_MODEL / 64, (BATCH * LSEQ) / 64);       // (8, 512)
  gemm512<<<gblk, 256, 0, stream>>>(query,  W_Q, nullptr, Q);
  gemm512<<<gblk, 256, 0, stream>>>(key_in, W_K, nullptr, K);
  gemm512<<<gblk, 256, 0, stream>>>(value,  W_V, nullptr, V);

  qk_sample_M<<<(BATCH * NHEADS * LSEQ) / 4, 256, 0, stream>>>(Q, K, sidx, M, S);
  topk_kernel<<<BATCH * NHEADS, 256, 0, stream>>>(M, Mtop, U);
  attn_rows<<<BATCH * NHEADS * U, 256, 0, stream>>>(Q, K, V, Mtop, ctxTop, U);
  vmean_kernel<<<BATCH * NHEADS, 256, 0, stream>>>(V, Vm);
  base_out_kernel<<<BATCH, 256, 0, stream>>>(Vm, W_out, b_out, baseO);
  fill_out<<<(BATCH * LSEQ * (D_MODEL / 4)) / 256, 256, 0, stream>>>(baseO, out);
  delta_out<<<BATCH * NHEADS * U, 256, 0, stream>>>(ctxTop, Vm, Mtop, W_out, out, U);
}

// Round 2
// 2138.970 us; speedup vs baseline: 1.6740x; 1.6740x over previous
//
#include <hip/hip_runtime.h>
#include <cstdint>
#include <cstddef>

#define D_MODEL 512
#define NHEADS  8
#define EDIM    64
#define BATCH   8
#define LSEQ    4096

// ======================= GEMM: Y = X @ W (+bias) ===========================
__global__ __launch_bounds__(256) void gemm512(
    const float* __restrict__ X, const float* __restrict__ W,
    const float* __restrict__ bias, float* __restrict__ Y) {
  __shared__ float As[16][68];
  __shared__ float Bs[16][68];
  const int tid = threadIdx.x;
  const int bm = blockIdx.y * 64;
  const int bn = blockIdx.x * 64;
  const int tx = tid & 15, ty = tid >> 4;
  const int m0 = ty * 4, n0 = tx * 4;
  const int am = tid >> 2, ak4 = (tid & 3) * 4;
  const int bk = tid >> 4, bn4 = (tid & 15) * 4;
  const float* Xp = X + (size_t)(bm + am) * D_MODEL + ak4;
  const float* Wp = W + (size_t)bk * D_MODEL + bn + bn4;
  float acc[4][4] = {};
  for (int k0 = 0; k0 < D_MODEL; k0 += 16) {
    float4 a  = *(const float4*)(Xp + k0);
    float4 bv = *(const float4*)(Wp + (size_t)k0 * D_MODEL);
    As[ak4 + 0][am] = a.x; As[ak4 + 1][am] = a.y;
    As[ak4 + 2][am] = a.z; As[ak4 + 3][am] = a.w;
    *(float4*)&Bs[bk][bn4] = bv;
    __syncthreads();
#pragma unroll
    for (int k = 0; k < 16; ++k) {
      float av[4], bw[4];
#pragma unroll
      for (int i = 0; i < 4; ++i) av[i] = As[k][m0 + i];
#pragma unroll
      for (int j = 0; j < 4; ++j) bw[j] = Bs[k][n0 + j];
#pragma unroll
      for (int i = 0; i < 4; ++i)
#pragma unroll
        for (int j = 0; j < 4; ++j) acc[i][j] += av[i] * bw[j];
    }
    __syncthreads();
  }
#pragma unroll
  for (int i = 0; i < 4; ++i) {
    float* yp = Y + (size_t)(bm + m0 + i) * D_MODEL + bn + n0;
#pragma unroll
    for (int j = 0; j < 4; ++j) {
      float bb = bias ? bias[bn + n0 + j] : 0.0f;
      yp[j] = acc[i][j] + bb;
    }
  }
}

// ================= QK_sample -> M = max - mean per (b,h,q) =================
__global__ __launch_bounds__(256) void qk_sample_M(
    const float* __restrict__ Q, const float* __restrict__ K,
    const int* __restrict__ sidx, float* __restrict__ M, int S) {
  int w = blockIdx.x * (blockDim.x >> 6) + (threadIdx.x >> 6);
  int lane = threadIdx.x & 63;
  int q = w & (LSEQ - 1);
  int bh = w >> 12;
  int h = bh & (NHEADS - 1);
  int b = bh >> 3;
  const float* Qrow = Q + ((size_t)b * LSEQ + q) * D_MODEL + h * EDIM;
  float qv = Qrow[lane];
  float mx = -3.4e38f, sum = 0.0f;
  for (int j = 0; j < S; ++j) {
    int kk = sidx[q * S + j];
    float kv = K[((size_t)b * LSEQ + kk) * D_MODEL + h * EDIM + lane];
    float p = qv * kv;
#pragma unroll
    for (int o = 32; o > 0; o >>= 1) p += __shfl_xor(p, o, 64);
    mx = fmaxf(mx, p);
    sum += p;
  }
  if (lane == 0) M[w] = mx - sum / (float)S;
}

// ===================== top-U indices per (b,h) =============================
__global__ __launch_bounds__(256) void topk_kernel(
    const float* __restrict__ M, int* __restrict__ Mtop, int U) {
  __shared__ float vals[LSEQ];
  __shared__ float rmax[256];
  __shared__ int ridx[256];
  int bh = blockIdx.x;
  int t = threadIdx.x;
  for (int i = t; i < LSEQ; i += 256) vals[i] = M[(size_t)bh * LSEQ + i];
  __syncthreads();
  for (int it = 0; it < U; ++it) {
    float best = -3.4e38f; int bi = -1;
    for (int i = t; i < LSEQ; i += 256) {
      float v = vals[i];
      if (v > best) { best = v; bi = i; }
    }
    rmax[t] = best; ridx[t] = bi;
    __syncthreads();
    for (int s = 128; s > 0; s >>= 1) {
      if (t < s) {
        if (rmax[t + s] > rmax[t]) { rmax[t] = rmax[t + s]; ridx[t] = ridx[t + s]; }
      }
      __syncthreads();
    }
    if (t == 0) {
      Mtop[(size_t)bh * U + it] = ridx[0];
      vals[ridx[0]] = -3.4e38f;
    }
    __syncthreads();
  }
}

// ============== flash attention over top-U rows, key-split =================
// lane = query index (U<=64 active). Each lane holds Q row + ctx in regs.
// Block handles one (bh, key-split); 4 waves split each 64-key LDS chunk.
__global__ __launch_bounds__(256) void attn_flash(
    const float* __restrict__ Q, const float* __restrict__ K,
    const float* __restrict__ V, const int* __restrict__ Mtop,
    float* __restrict__ part_ctx, float* __restrict__ part_m,
    float* __restrict__ part_l, int U, int nsplit, int chunks_per_block) {
  __shared__ float Ks[64 * 64];       // [key][e], reused as ctx accum [e][u]
  __shared__ float Vs[64 * 64];       // [key][e]
  __shared__ float Mw[4][64], Lw[4][64];
  const int bh = blockIdx.y, split = blockIdx.x;
  const int h = bh & (NHEADS - 1), b = bh >> 3;
  const int t = threadIdx.x, w = t >> 6, lane = t & 63;

  int qrow = (lane < U) ? Mtop[(size_t)bh * U + lane] : 0;
  const float4* Qp = (const float4*)(Q + ((size_t)(b * LSEQ) + qrow) * D_MODEL + h * EDIM);
  float4 q4[16], c4[16];
#pragma unroll
  for (int i = 0; i < 16; ++i) q4[i] = Qp[i];
#pragma unroll
  for (int i = 0; i < 16; ++i) c4[i] = make_float4(0.f, 0.f, 0.f, 0.f);
  float m = -1e30f, l = 0.0f;

  const int k_base = split * (chunks_per_block * 64);
  for (int c = 0; c < chunks_per_block; ++c) {
    const int k0 = k_base + c * 64;
    const float4* Kg = (const float4*)(K + ((size_t)(b * LSEQ) + k0) * D_MODEL + h * EDIM);
    const float4* Vg = (const float4*)(V + ((size_t)(b * LSEQ) + k0) * D_MODEL + h * EDIM);
#pragma unroll
    for (int i = 0; i < 4; ++i) {
      int f = t + i * 256;              // 0..1023: row = f>>4, col4 = f&15
      int row = f >> 4, col4 = f & 15;
      ((float4*)Ks)[f] = Kg[(size_t)row * 128 + col4];
      ((float4*)Vs)[f] = Vg[(size_t)row * 128 + col4];
    }
    __syncthreads();
#pragma unroll 1
    for (int rr = 0; rr < 16; ++rr) {
      const int r = w * 16 + rr;
      const float4* kr = (const float4*)&Ks[r * 64];
      float s = 0.0f;
#pragma unroll
      for (int i = 0; i < 16; ++i) {
        float4 kv = kr[i];              // LDS broadcast (wave-uniform addr)
        s += q4[i].x * kv.x + q4[i].y * kv.y + q4[i].z * kv.z + q4[i].w * kv.w;
      }
      s *= 0.125f;                      // 1/sqrt(64)
      if (s > m) {                      // rare after warm-up
        float f = __expf(m - s);
        l *= f;
#pragma unroll
        for (int i = 0; i < 16; ++i) {
          c4[i].x *= f; c4[i].y *= f; c4[i].z *= f; c4[i].w *= f;
        }
        m = s;
      }
      float p = __expf(s - m);
      l += p;
      const float4* vr = (const float4*)&Vs[r * 64];
#pragma unroll
      for (int i = 0; i < 16; ++i) {
        float4 vv = vr[i];              // LDS broadcast
        c4[i].x += p * vv.x; c4[i].y += p * vv.y;
        c4[i].z += p * vv.z; c4[i].w += p * vv.w;
      }
    }
    __syncthreads();
  }

  // ---- cross-wave combine within block ----
  Mw[w][lane] = m; Lw[w][lane] = l;
  __syncthreads();
  float Mg = fmaxf(fmaxf(Mw[0][lane], Mw[1][lane]), fmaxf(Mw[2][lane], Mw[3][lane]));
  float Lg = 0.0f;
#pragma unroll
  for (int w2 = 0; w2 < 4; ++w2) Lg += Lw[w2][lane] * __expf(Mw[w2][lane] - Mg);
  float sw = __expf(m - Mg);
  float* acc = Ks;                      // reuse as [e][u]
  for (int w2 = 0; w2 < 4; ++w2) {
    if (w == w2) {
#pragma unroll
      for (int i = 0; i < 16; ++i) {
        int e = i * 4;
        if (w2 == 0) {
          acc[(e + 0) * 64 + lane] = c4[i].x * sw;
          acc[(e + 1) * 64 + lane] = c4[i].y * sw;
          acc[(e + 2) * 64 + lane] = c4[i].z * sw;
          acc[(e + 3) * 64 + lane] = c4[i].w * sw;
        } else {
          acc[(e + 0) * 64 + lane] += c4[i].x * sw;
          acc[(e + 1) * 64 + lane] += c4[i].y * sw;
          acc[(e + 2) * 64 + lane] += c4[i].z * sw;
          acc[(e + 3) * 64 + lane] += c4[i].w * sw;
        }
      }
    }
    __syncthreads();
  }
  if (w == 0 && lane < U) {
    part_m[(size_t)(bh * nsplit + split) * 64 + lane] = Mg;
    part_l[(size_t)(bh * nsplit + split) * 64 + lane] = Lg;
  }
  float* pc = part_ctx + (size_t)(bh * nsplit + split) * 4096;   // [e][u]
#pragma unroll
  for (int i = 0; i < 16; ++i) {
    int f = t + i * 256;
    pc[f] = acc[f];
  }
}

// =================== combine key-split flash partials ======================
__global__ __launch_bounds__(256) void attn_combine(
    const float* __restrict__ part_ctx, const float* __restrict__ part_m,
    const float* __restrict__ part_l, float* __restrict__ ctxTop,
    int U, int nsplit) {
  __shared__ float F[16][64];
  const int bh = blockIdx.x;
  const int t = threadIdx.x, lane = t & 63, grp = t >> 6;
  if (grp == 0) {
    float M = -3.4e38f;
    for (int s = 0; s < nsplit; ++s)
      M = fmaxf(M, part_m[(size_t)(bh * nsplit + s) * 64 + lane]);
    float L = 0.0f;
    for (int s = 0; s < nsplit; ++s)
      L += part_l[(size_t)(bh * nsplit + s) * 64 + lane] *
           __expf(part_m[(size_t)(bh * nsplit + s) * 64 + lane] - M);
    float invL = 1.0f / L;
    for (int s = 0; s < nsplit; ++s)
      F[s][lane] = __expf(part_m[(size_t)(bh * nsplit + s) * 64 + lane] - M) * invL;
  }
  __syncthreads();
  for (int ei = 0; ei < 16; ++ei) {
    int e = grp * 16 + ei;
    float acc = 0.0f;
    for (int s = 0; s < nsplit; ++s)
      acc += F[s][lane] * part_ctx[(size_t)(bh * nsplit + s) * 4096 + e * 64 + lane];
    if (lane < U) ctxTop[((size_t)bh * U + lane) * 64 + e] = acc;
  }
}

// ====================== V.mean over keys per (b,h) =========================
__global__ __launch_bounds__(256) void vmean_kernel(
    const float* __restrict__ V, float* __restrict__ Vm) {
  __shared__ float part[4][EDIM];
  int bh = blockIdx.x;
  int h = bh & (NHEADS - 1), b = bh >> 3;
  int t = threadIdx.x;
  int e = t & 63, c = t >> 6;
  float s = 0.0f;
  for (int k = c * (LSEQ / 4); k < (c + 1) * (LSEQ / 4); ++k)
    s += V[((size_t)b * LSEQ + k) * D_MODEL + h * EDIM + e];
  part[c][e] = s;
  __syncthreads();
  if (c == 0)
    Vm[(size_t)bh * EDIM + e] =
        (part[0][e] + part[1][e] + part[2][e] + part[3][e]) * (1.0f / (float)LSEQ);
}

// ============ base_out[b] = concat_h(Vmean[b,h]) @ W_out + b_out ===========
__global__ __launch_bounds__(256) void base_out_kernel(
    const float* __restrict__ Vm, const float* __restrict__ Wout,
    const float* __restrict__ bout, float* __restrict__ base) {
  __shared__ float cb[D_MODEL];
  int b = blockIdx.x;
  int t = threadIdx.x;
  for (int d = t; d < D_MODEL; d += 256) cb[d] = Vm[(size_t)b * D_MODEL + d];
  __syncthreads();
  for (int n = t; n < D_MODEL; n += 256) {
    float s = bout[n];
    for (int d = 0; d < D_MODEL; ++d) s += cb[d] * Wout[(size_t)d * D_MODEL + n];
    base[(size_t)b * D_MODEL + n] = s;
  }
}

// ================== broadcast base row into all output rows ================
__global__ __launch_bounds__(256) void fill_out(
    const float* __restrict__ base, float* __restrict__ out) {
  size_t i = (size_t)blockIdx.x * 256 + threadIdx.x;
  int n4 = (int)(i & 127);
  size_t bq = i >> 7;
  int b = (int)(bq >> 12);
  float4 v = ((const float4*)base)[(size_t)b * 128 + n4];
  ((float4*)out)[i] = v;
}

// ====== add (ctxTop - Vmean) @ W_out[h-slice] into the top rows ============
__global__ __launch_bounds__(256) void delta_out(
    const float* __restrict__ ctxTop, const float* __restrict__ Vm,
    const int* __restrict__ Mtop, const float* __restrict__ Wout,
    float* __restrict__ out, int U) {
  __shared__ float dlt[EDIM];
  int blk = blockIdx.x;
  int u = blk % U, bh = blk / U;
  int h = bh & (NHEADS - 1), b = bh >> 3;
  int q = Mtop[(size_t)bh * U + u];
  int t = threadIdx.x;
  if (t < EDIM)
    dlt[t] = ctxTop[((size_t)bh * U + u) * EDIM + t] - Vm[(size_t)bh * EDIM + t];
  __syncthreads();
  float* orow = out + ((size_t)b * LSEQ + q) * D_MODEL;
  for (int n = t; n < D_MODEL; n += 256) {
    float s = 0.0f;
#pragma unroll
    for (int e = 0; e < EDIM; ++e) s += dlt[e] * Wout[(size_t)(h * EDIM + e) * D_MODEL + n];
    atomicAdd(&orow[n], s);
  }
}

// ===========================================================================
extern "C" void kernel_launch(void* const* d_in, const int* in_sizes, int n_in,
                              void* d_out, int out_size, void* d_ws, size_t ws_size,
                              hipStream_t stream) {
  const float* query  = (const float*)d_in[0];
  const float* key_in = (const float*)d_in[1];
  const float* value  = (const float*)d_in[2];
  const float* W_Q    = (const float*)d_in[3];
  const float* W_K    = (const float*)d_in[4];
  const float* W_V    = (const float*)d_in[5];
  const float* W_out  = (const float*)d_in[6];
  const float* b_out  = (const float*)d_in[7];
  const int*   sidx   = (const int*)d_in[8];
  float* out = (float*)d_out;

  const int S = in_sizes[8] / LSEQ;   // 41
  const int U = S;

  char* ws = (char*)d_ws;
  size_t o = 0;
  float* Q      = (float*)(ws + o); o += (size_t)BATCH * LSEQ * D_MODEL * 4;
  float* K      = (float*)(ws + o); o += (size_t)BATCH * LSEQ * D_MODEL * 4;
  float* V      = (float*)(ws + o); o += (size_t)BATCH * LSEQ * D_MODEL * 4;
  int*   Mtop   = (int*)  (ws + o); o += ((size_t)64 * U * 4 + 255) & ~255ULL;
  float* ctxTop = (float*)(ws + o); o += ((size_t)64 * U * EDIM * 4 + 255) & ~255ULL;
  float* Vm     = (float*)(ws + o); o += 16384;
  float* baseO  = (float*)(ws + o); o += 16384;
  size_t unionOff = o;                 // M overlaps flash partials (disjoint lifetimes)
  float* M = (float*)(ws + unionOff);  // 64*4096*4 = 1 MB

  int nsplit = 16;
  for (;;) {
    size_t need = unionOff + 2 * ((size_t)64 * nsplit * 64 * 4)
                  + (size_t)64 * nsplit * 4096 * 4;
    size_t mneed = unionOff + (size_t)64 * LSEQ * 4;
    if ((need <= ws_size && mneed <= ws_size) || nsplit == 1) break;
    nsplit >>= 1;
  }
  float* part_m   = (float*)(ws + unionOff);
  float* part_l   = part_m + (size_t)64 * nsplit * 64;
  float* part_ctx = part_l + (size_t)64 * nsplit * 64;
  const int chunks_per_block = 64 / nsplit;

  dim3 gblk(D_MODEL / 64, (BATCH * LSEQ) / 64);
  gemm512<<<gblk, 256, 0, stream>>>(query,  W_Q, nullptr, Q);
  gemm512<<<gblk, 256, 0, stream>>>(key_in, W_K, nullptr, K);
  gemm512<<<gblk, 256, 0, stream>>>(value,  W_V, nullptr, V);

  qk_sample_M<<<(BATCH * NHEADS * LSEQ) / 4, 256, 0, stream>>>(Q, K, sidx, M, S);
  topk_kernel<<<BATCH * NHEADS, 256, 0, stream>>>(M, Mtop, U);
  attn_flash<<<dim3(nsplit, BATCH * NHEADS), 256, 0, stream>>>(
      Q, K, V, Mtop, part_ctx, part_m, part_l, U, nsplit, chunks_per_block);
  attn_combine<<<BATCH * NHEADS, 256, 0, stream>>>(
      part_ctx, part_m, part_l, ctxTop, U, nsplit);
  vmean_kernel<<<BATCH * NHEADS, 256, 0, stream>>>(V, Vm);
  base_out_kernel<<<BATCH, 256, 0, stream>>>(Vm, W_out, b_out, baseO);
  fill_out<<<(BATCH * LSEQ * (D_MODEL / 4)) / 256, 256, 0, stream>>>(baseO, out);
  delta_out<<<BATCH * NHEADS * U, 256, 0, stream>>>(ctxTop, Vm, Mtop, W_out, out, U);
}

// Round 3
// 1544.885 us; speedup vs baseline: 2.3177x; 1.3846x over previous
//
#include <hip/hip_runtime.h>
#include <cstdint>
#include <cstddef>

#define D_MODEL 512
#define NHEADS  8
#define EDIM    64
#define BATCH   8
#define LSEQ    4096

// ======================= GEMM: Y = X @ W (+bias) ===========================
__global__ __launch_bounds__(256) void gemm512(
    const float* __restrict__ X, const float* __restrict__ W,
    const float* __restrict__ bias, float* __restrict__ Y) {
  __shared__ float As[16][68];
  __shared__ float Bs[16][68];
  const int tid = threadIdx.x;
  const int bm = blockIdx.y * 64;
  const int bn = blockIdx.x * 64;
  const int tx = tid & 15, ty = tid >> 4;
  const int m0 = ty * 4, n0 = tx * 4;
  const int am = tid >> 2, ak4 = (tid & 3) * 4;
  const int bk = tid >> 4, bn4 = (tid & 15) * 4;
  const float* Xp = X + (size_t)(bm + am) * D_MODEL + ak4;
  const float* Wp = W + (size_t)bk * D_MODEL + bn + bn4;
  float acc[4][4] = {};
  for (int k0 = 0; k0 < D_MODEL; k0 += 16) {
    float4 a  = *(const float4*)(Xp + k0);
    float4 bv = *(const float4*)(Wp + (size_t)k0 * D_MODEL);
    As[ak4 + 0][am] = a.x; As[ak4 + 1][am] = a.y;
    As[ak4 + 2][am] = a.z; As[ak4 + 3][am] = a.w;
    *(float4*)&Bs[bk][bn4] = bv;
    __syncthreads();
#pragma unroll
    for (int k = 0; k < 16; ++k) {
      float av[4], bw[4];
#pragma unroll
      for (int i = 0; i < 4; ++i) av[i] = As[k][m0 + i];
#pragma unroll
      for (int j = 0; j < 4; ++j) bw[j] = Bs[k][n0 + j];
#pragma unroll
      for (int i = 0; i < 4; ++i)
#pragma unroll
        for (int j = 0; j < 4; ++j) acc[i][j] += av[i] * bw[j];
    }
    __syncthreads();
  }
#pragma unroll
  for (int i = 0; i < 4; ++i) {
    float* yp = Y + (size_t)(bm + m0 + i) * D_MODEL + bn + n0;
#pragma unroll
    for (int j = 0; j < 4; ++j) {
      float bb = bias ? bias[bn + n0 + j] : 0.0f;
      yp[j] = acc[i][j] + bb;
    }
  }
}

// ================= QK_sample -> M = max - mean per (b,h,q) =================
// One wave per (b,q), ALL 8 heads at once. lane = h*8 + part; lane owns
// 8 consecutive e of head h. Full 2KB K row fetched once; 3 shuffles finish
// all 8 head-dots simultaneously. Next-row prefetch hides gather latency.
__global__ __launch_bounds__(256) void qk_sample_M(
    const float* __restrict__ Q, const float* __restrict__ K,
    const int* __restrict__ sidx, float* __restrict__ M, int S) {
  const int w = blockIdx.x * 4 + (threadIdx.x >> 6);
  const int lane = threadIdx.x & 63;
  const int q = w & (LSEQ - 1);
  const int b = w >> 12;
  const int part = lane & 7, h = lane >> 3;

  const float* Qrow = Q + ((size_t)b * LSEQ + q) * D_MODEL + lane * 8;
  float4 qa = ((const float4*)Qrow)[0];
  float4 qb = ((const float4*)Qrow)[1];

  const float* Kb = K + (size_t)b * LSEQ * D_MODEL;
  const int* sp = sidx + (size_t)q * S;

  float mx = -3.4e38f, sum = 0.0f;
  int kk = sp[0];
  const float4* kr = (const float4*)(Kb + (size_t)kk * D_MODEL + lane * 8);
  float4 ka = kr[0], kb4 = kr[1];
  for (int j = 0; j < S; ++j) {
    float4 ca = ka, cb = kb4;
    if (j + 1 < S) {
      int kn = sp[j + 1];
      const float4* krn = (const float4*)(Kb + (size_t)kn * D_MODEL + lane * 8);
      ka = krn[0]; kb4 = krn[1];
    }
    float p = qa.x * ca.x + qa.y * ca.y + qa.z * ca.z + qa.w * ca.w +
              qb.x * cb.x + qb.y * cb.y + qb.z * cb.z + qb.w * cb.w;
    p += __shfl_xor(p, 1, 64);
    p += __shfl_xor(p, 2, 64);
    p += __shfl_xor(p, 4, 64);   // lanes of head h now all hold the full dot
    mx = fmaxf(mx, p);
    sum += p;
  }
  if (part == 0) M[((size_t)(b * NHEADS + h)) * LSEQ + q] = mx - sum / (float)S;
}

// ===================== top-U indices per (b,h) =============================
__global__ __launch_bounds__(256) void topk_kernel(
    const float* __restrict__ M, int* __restrict__ Mtop, int U) {
  __shared__ float vals[LSEQ];
  __shared__ float rmax[256];
  __shared__ int ridx[256];
  int bh = blockIdx.x;
  int t = threadIdx.x;
  for (int i = t; i < LSEQ; i += 256) vals[i] = M[(size_t)bh * LSEQ + i];
  __syncthreads();
  for (int it = 0; it < U; ++it) {
    float best = -3.4e38f; int bi = -1;
    for (int i = t; i < LSEQ; i += 256) {
      float v = vals[i];
      if (v > best) { best = v; bi = i; }
    }
    rmax[t] = best; ridx[t] = bi;
    __syncthreads();
    for (int s = 128; s > 0; s >>= 1) {
      if (t < s) {
        if (rmax[t + s] > rmax[t]) { rmax[t] = rmax[t + s]; ridx[t] = ridx[t + s]; }
      }
      __syncthreads();
    }
    if (t == 0) {
      Mtop[(size_t)bh * U + it] = ridx[0];
      vals[ridx[0]] = -3.4e38f;
    }
    __syncthreads();
  }
}

// ============== flash attention over top-U rows, key-split =================
__global__ __launch_bounds__(256) void attn_flash(
    const float* __restrict__ Q, const float* __restrict__ K,
    const float* __restrict__ V, const int* __restrict__ Mtop,
    float* __restrict__ part_ctx, float* __restrict__ part_m,
    float* __restrict__ part_l, int U, int nsplit, int chunks_per_block) {
  __shared__ float Ks[64 * 64];       // [key][e], reused as ctx accum [e][u]
  __shared__ float Vs[64 * 64];       // [key][e]
  __shared__ float Mw[4][64], Lw[4][64];
  const int bh = blockIdx.y, split = blockIdx.x;
  const int h = bh & (NHEADS - 1), b = bh >> 3;
  const int t = threadIdx.x, w = t >> 6, lane = t & 63;

  int qrow = (lane < U) ? Mtop[(size_t)bh * U + lane] : 0;
  const float4* Qp = (const float4*)(Q + ((size_t)(b * LSEQ) + qrow) * D_MODEL + h * EDIM);
  float4 q4[16], c4[16];
#pragma unroll
  for (int i = 0; i < 16; ++i) q4[i] = Qp[i];
#pragma unroll
  for (int i = 0; i < 16; ++i) c4[i] = make_float4(0.f, 0.f, 0.f, 0.f);
  float m = -1e30f, l = 0.0f;

  const int k_base = split * (chunks_per_block * 64);
  for (int c = 0; c < chunks_per_block; ++c) {
    const int k0 = k_base + c * 64;
    const float4* Kg = (const float4*)(K + ((size_t)(b * LSEQ) + k0) * D_MODEL + h * EDIM);
    const float4* Vg = (const float4*)(V + ((size_t)(b * LSEQ) + k0) * D_MODEL + h * EDIM);
#pragma unroll
    for (int i = 0; i < 4; ++i) {
      int f = t + i * 256;
      int row = f >> 4, col4 = f & 15;
      ((float4*)Ks)[f] = Kg[(size_t)row * 128 + col4];
      ((float4*)Vs)[f] = Vg[(size_t)row * 128 + col4];
    }
    __syncthreads();
#pragma unroll 1
    for (int rr = 0; rr < 16; ++rr) {
      const int r = w * 16 + rr;
      const float4* kr = (const float4*)&Ks[r * 64];
      float s = 0.0f;
#pragma unroll
      for (int i = 0; i < 16; ++i) {
        float4 kv = kr[i];
        s += q4[i].x * kv.x + q4[i].y * kv.y + q4[i].z * kv.z + q4[i].w * kv.w;
      }
      s *= 0.125f;
      if (s > m) {
        float f = __expf(m - s);
        l *= f;
#pragma unroll
        for (int i = 0; i < 16; ++i) {
          c4[i].x *= f; c4[i].y *= f; c4[i].z *= f; c4[i].w *= f;
        }
        m = s;
      }
      float p = __expf(s - m);
      l += p;
      const float4* vr = (const float4*)&Vs[r * 64];
#pragma unroll
      for (int i = 0; i < 16; ++i) {
        float4 vv = vr[i];
        c4[i].x += p * vv.x; c4[i].y += p * vv.y;
        c4[i].z += p * vv.z; c4[i].w += p * vv.w;
      }
    }
    __syncthreads();
  }

  Mw[w][lane] = m; Lw[w][lane] = l;
  __syncthreads();
  float Mg = fmaxf(fmaxf(Mw[0][lane], Mw[1][lane]), fmaxf(Mw[2][lane], Mw[3][lane]));
  float Lg = 0.0f;
#pragma unroll
  for (int w2 = 0; w2 < 4; ++w2) Lg += Lw[w2][lane] * __expf(Mw[w2][lane] - Mg);
  float sw = __expf(m - Mg);
  float* acc = Ks;
  for (int w2 = 0; w2 < 4; ++w2) {
    if (w == w2) {
#pragma unroll
      for (int i = 0; i < 16; ++i) {
        int e = i * 4;
        if (w2 == 0) {
          acc[(e + 0) * 64 + lane] = c4[i].x * sw;
          acc[(e + 1) * 64 + lane] = c4[i].y * sw;
          acc[(e + 2) * 64 + lane] = c4[i].z * sw;
          acc[(e + 3) * 64 + lane] = c4[i].w * sw;
        } else {
          acc[(e + 0) * 64 + lane] += c4[i].x * sw;
          acc[(e + 1) * 64 + lane] += c4[i].y * sw;
          acc[(e + 2) * 64 + lane] += c4[i].z * sw;
          acc[(e + 3) * 64 + lane] += c4[i].w * sw;
        }
      }
    }
    __syncthreads();
  }
  if (w == 0 && lane < U) {
    part_m[(size_t)(bh * nsplit + split) * 64 + lane] = Mg;
    part_l[(size_t)(bh * nsplit + split) * 64 + lane] = Lg;
  }
  float* pc = part_ctx + (size_t)(bh * nsplit + split) * 4096;
#pragma unroll
  for (int i = 0; i < 16; ++i) {
    int f = t + i * 256;
    pc[f] = acc[f];
  }
}

// =================== combine key-split flash partials ======================
__global__ __launch_bounds__(256) void attn_combine(
    const float* __restrict__ part_ctx, const float* __restrict__ part_m,
    const float* __restrict__ part_l, float* __restrict__ ctxTop,
    int U, int nsplit) {
  __shared__ float F[16][64];
  const int bh = blockIdx.x;
  const int t = threadIdx.x, lane = t & 63, grp = t >> 6;
  if (grp == 0) {
    float M = -3.4e38f;
    for (int s = 0; s < nsplit; ++s)
      M = fmaxf(M, part_m[(size_t)(bh * nsplit + s) * 64 + lane]);
    float L = 0.0f;
    for (int s = 0; s < nsplit; ++s)
      L += part_l[(size_t)(bh * nsplit + s) * 64 + lane] *
           __expf(part_m[(size_t)(bh * nsplit + s) * 64 + lane] - M);
    float invL = 1.0f / L;
    for (int s = 0; s < nsplit; ++s)
      F[s][lane] = __expf(part_m[(size_t)(bh * nsplit + s) * 64 + lane] - M) * invL;
  }
  __syncthreads();
  for (int ei = 0; ei < 16; ++ei) {
    int e = grp * 16 + ei;
    float acc = 0.0f;
    for (int s = 0; s < nsplit; ++s)
      acc += F[s][lane] * part_ctx[(size_t)(bh * nsplit + s) * 4096 + e * 64 + lane];
    if (lane < U) ctxTop[((size_t)bh * U + lane) * 64 + e] = acc;
  }
}

// ====================== V.mean over keys per (b,h) =========================
__global__ __launch_bounds__(256) void vmean_kernel(
    const float* __restrict__ V, float* __restrict__ Vm) {
  __shared__ float part[4][EDIM];
  int bh = blockIdx.x;
  int h = bh & (NHEADS - 1), b = bh >> 3;
  int t = threadIdx.x;
  int e = t & 63, c = t >> 6;
  float s = 0.0f;
  for (int k = c * (LSEQ / 4); k < (c + 1) * (LSEQ / 4); ++k)
    s += V[((size_t)b * LSEQ + k) * D_MODEL + h * EDIM + e];
  part[c][e] = s;
  __syncthreads();
  if (c == 0)
    Vm[(size_t)bh * EDIM + e] =
        (part[0][e] + part[1][e] + part[2][e] + part[3][e]) * (1.0f / (float)LSEQ);
}

// ============ base_out[b] = concat_h(Vmean[b,h]) @ W_out + b_out ===========
__global__ __launch_bounds__(256) void base_out_kernel(
    const float* __restrict__ Vm, const float* __restrict__ Wout,
    const float* __restrict__ bout, float* __restrict__ base) {
  __shared__ float cb[D_MODEL];
  int b = blockIdx.x;
  int t = threadIdx.x;
  for (int d = t; d < D_MODEL; d += 256) cb[d] = Vm[(size_t)b * D_MODEL + d];
  __syncthreads();
  for (int n = t; n < D_MODEL; n += 256) {
    float s = bout[n];
    for (int d = 0; d < D_MODEL; ++d) s += cb[d] * Wout[(size_t)d * D_MODEL + n];
    base[(size_t)b * D_MODEL + n] = s;
  }
}

// ================== broadcast base row into all output rows ================
__global__ __launch_bounds__(256) void fill_out(
    const float* __restrict__ base, float* __restrict__ out) {
  size_t i = (size_t)blockIdx.x * 256 + threadIdx.x;
  int n4 = (int)(i & 127);
  size_t bq = i >> 7;
  int b = (int)(bq >> 12);
  float4 v = ((const float4*)base)[(size_t)b * 128 + n4];
  ((float4*)out)[i] = v;
}

// ====== add (ctxTop - Vmean) @ W_out[h-slice] into the top rows ============
__global__ __launch_bounds__(256) void delta_out(
    const float* __restrict__ ctxTop, const float* __restrict__ Vm,
    const int* __restrict__ Mtop, const float* __restrict__ Wout,
    float* __restrict__ out, int U) {
  __shared__ float dlt[EDIM];
  int blk = blockIdx.x;
  int u = blk % U, bh = blk / U;
  int h = bh & (NHEADS - 1), b = bh >> 3;
  int q = Mtop[(size_t)bh * U + u];
  int t = threadIdx.x;
  if (t < EDIM)
    dlt[t] = ctxTop[((size_t)bh * U + u) * EDIM + t] - Vm[(size_t)bh * EDIM + t];
  __syncthreads();
  float* orow = out + ((size_t)b * LSEQ + q) * D_MODEL;
  for (int n = t; n < D_MODEL; n += 256) {
    float s = 0.0f;
#pragma unroll
    for (int e = 0; e < EDIM; ++e) s += dlt[e] * Wout[(size_t)(h * EDIM + e) * D_MODEL + n];
    atomicAdd(&orow[n], s);
  }
}

// ===========================================================================
extern "C" void kernel_launch(void* const* d_in, const int* in_sizes, int n_in,
                              void* d_out, int out_size, void* d_ws, size_t ws_size,
                              hipStream_t stream) {
  const float* query  = (const float*)d_in[0];
  const float* key_in = (const float*)d_in[1];
  const float* value  = (const float*)d_in[2];
  const float* W_Q    = (const float*)d_in[3];
  const float* W_K    = (const float*)d_in[4];
  const float* W_V    = (const float*)d_in[5];
  const float* W_out  = (const float*)d_in[6];
  const float* b_out  = (const float*)d_in[7];
  const int*   sidx   = (const int*)d_in[8];
  float* out = (float*)d_out;

  const int S = in_sizes[8] / LSEQ;   // 41
  const int U = S;

  char* ws = (char*)d_ws;
  size_t o = 0;
  float* Q      = (float*)(ws + o); o += (size_t)BATCH * LSEQ * D_MODEL * 4;
  float* K      = (float*)(ws + o); o += (size_t)BATCH * LSEQ * D_MODEL * 4;
  float* V      = (float*)(ws + o); o += (size_t)BATCH * LSEQ * D_MODEL * 4;
  int*   Mtop   = (int*)  (ws + o); o += ((size_t)64 * U * 4 + 255) & ~255ULL;
  float* ctxTop = (float*)(ws + o); o += ((size_t)64 * U * EDIM * 4 + 255) & ~255ULL;
  float* Vm     = (float*)(ws + o); o += 16384;
  float* baseO  = (float*)(ws + o); o += 16384;
  size_t unionOff = o;                 // M overlaps flash partials (disjoint lifetimes)
  float* M = (float*)(ws + unionOff);  // 64*4096*4 = 1 MB

  int nsplit = 16;
  for (;;) {
    size_t need = unionOff + 2 * ((size_t)64 * nsplit * 64 * 4)
                  + (size_t)64 * nsplit * 4096 * 4;
    size_t mneed = unionOff + (size_t)64 * LSEQ * 4;
    if ((need <= ws_size && mneed <= ws_size) || nsplit == 1) break;
    nsplit >>= 1;
  }
  float* part_m   = (float*)(ws + unionOff);
  float* part_l   = part_m + (size_t)64 * nsplit * 64;
  float* part_ctx = part_l + (size_t)64 * nsplit * 64;
  const int chunks_per_block = 64 / nsplit;

  dim3 gblk(D_MODEL / 64, (BATCH * LSEQ) / 64);
  gemm512<<<gblk, 256, 0, stream>>>(query,  W_Q, nullptr, Q);
  gemm512<<<gblk, 256, 0, stream>>>(key_in, W_K, nullptr, K);
  gemm512<<<gblk, 256, 0, stream>>>(value,  W_V, nullptr, V);

  qk_sample_M<<<(BATCH * LSEQ) / 4, 256, 0, stream>>>(Q, K, sidx, M, S);
  topk_kernel<<<BATCH * NHEADS, 256, 0, stream>>>(M, Mtop, U);
  attn_flash<<<dim3(nsplit, BATCH * NHEADS), 256, 0, stream>>>(
      Q, K, V, Mtop, part_ctx, part_m, part_l, U, nsplit, chunks_per_block);
  attn_combine<<<BATCH * NHEADS, 256, 0, stream>>>(
      part_ctx, part_m, part_l, ctxTop, U, nsplit);
  vmean_kernel<<<BATCH * NHEADS, 256, 0, stream>>>(V, Vm);
  base_out_kernel<<<BATCH, 256, 0, stream>>>(Vm, W_out, b_out, baseO);
  fill_out<<<(BATCH * LSEQ * (D_MODEL / 4)) / 256, 256, 0, stream>>>(baseO, out);
  delta_out<<<BATCH * NHEADS * U, 256, 0, stream>>>(ctxTop, Vm, Mtop, W_out, out, U);
}

// Round 4
// 1366.375 us; speedup vs baseline: 2.6206x; 1.1306x over previous
//
#include <hip/hip_runtime.h>
#include <cstdint>
#include <cstddef>

#define D_MODEL 512
#define NHEADS  8
#define EDIM    64
#define BATCH   8
#define LSEQ    4096

typedef unsigned short u16;
typedef __attribute__((ext_vector_type(8))) short short8;
typedef __attribute__((ext_vector_type(4))) float f32x4;

// ===================== fp32 -> exact 3-term bf16 split =====================
__device__ __forceinline__ u16 bf16_rne(float x) {
  unsigned int u = __float_as_uint(x);
  u += 0x7FFFu + ((u >> 16) & 1u);
  return (u16)(u >> 16);
}
__device__ __forceinline__ void split3(float x, u16& h, u16& l, u16& l2) {
  h = bf16_rne(x);
  float hf = __uint_as_float((unsigned int)h << 16);
  float r1 = x - hf;
  l = bf16_rne(r1);
  float lf = __uint_as_float((unsigned int)l << 16);
  l2 = bf16_rne(r1 - lf);          // exact: remaining <=8 significant bits
}

// X (fp32, Mchunk x 512) -> 3 bf16 planes (h, l, l2), each planeStride elems
__global__ __launch_bounds__(256) void cvt_x(
    const float* __restrict__ X, u16* __restrict__ P, int planeStride) {
  size_t i = ((size_t)blockIdx.x * 256 + threadIdx.x) * 4;
  float4 x = *(const float4*)(X + i);
  ushort4 h, l, l2;
  split3(x.x, h.x, l.x, l2.x);
  split3(x.y, h.y, l.y, l2.y);
  split3(x.z, h.z, l.z, l2.z);
  split3(x.w, h.w, l.w, l2.w);
  *(ushort4*)(P + i) = h;
  *(ushort4*)(P + planeStride + i) = l;
  *(ushort4*)(P + 2 * (size_t)planeStride + i) = l2;
}

// W (512x512 fp32, k-major) -> transposed planes WT[n][k] (h,l,l2), 3 weights
__global__ __launch_bounds__(256) void cvt_w(
    const float* __restrict__ W0, const float* __restrict__ W1,
    const float* __restrict__ W2, u16* __restrict__ out) {
  const float* W = (blockIdx.z == 0) ? W0 : ((blockIdx.z == 1) ? W1 : W2);
  u16* P = out + (size_t)blockIdx.z * 786432;       // 3 planes of 262144
  __shared__ float tile[64][65];
  const int k0 = blockIdx.x * 64, n0 = blockIdx.y * 64;
  const int t = threadIdx.x;
  const int tr = t >> 4, tc = (t & 15) * 4;
#pragma unroll
  for (int j = 0; j < 4; ++j) {
    int kr = tr + j * 16;
    float4 v = *(const float4*)(W + (size_t)(k0 + kr) * 512 + n0 + tc);
    tile[kr][tc + 0] = v.x; tile[kr][tc + 1] = v.y;
    tile[kr][tc + 2] = v.z; tile[kr][tc + 3] = v.w;
  }
  __syncthreads();
#pragma unroll
  for (int j = 0; j < 4; ++j) {
    int nr = tr + j * 16;
    ushort4 h, l, l2;
    float x0 = tile[tc + 0][nr], x1 = tile[tc + 1][nr];
    float x2 = tile[tc + 2][nr], x3 = tile[tc + 3][nr];
    split3(x0, h.x, l.x, l2.x);
    split3(x1, h.y, l.y, l2.y);
    split3(x2, h.z, l.z, l2.z);
    split3(x3, h.w, l.w, l2.w);
    size_t off = (size_t)(n0 + nr) * 512 + k0 + tc;
    *(ushort4*)(P + off) = h;
    *(ushort4*)(P + 262144 + off) = l;
    *(ushort4*)(P + 524288 + off) = l2;
  }
}

// ========== split-bf16 MFMA GEMM: Y = X @ W, fp32-accurate ================
// 128x128 tile, BK=32, 4 waves (2x2 of 64x64). K-loop runs npass passes of
// 16 k-steps, selecting (Xh|Xl|Xl2) x (Wh|Wl|Wl2) planes per pass.
__global__ __launch_bounds__(256) void gemm_mfma(
    const u16* __restrict__ XP, int xPlaneStride,
    const u16* __restrict__ WP, float* __restrict__ Y, int npass) {
  __shared__ u16 As[128 * 32];
  __shared__ u16 Bs[128 * 32];
  const int tid = threadIdx.x;
  const int lane = tid & 63, wv = tid >> 6;
  const int wm = (wv & 1) * 64, wn = (wv >> 1) * 64;
  const int bm = blockIdx.x * 128, bn = blockIdx.y * 128;
  const int fr = lane & 15, quad = lane >> 4;
  const int sRow = tid >> 2, sColB = (tid & 3) * 16;

  f32x4 acc[16];
#pragma unroll
  for (int i = 0; i < 16; ++i) acc[i] = (f32x4){0.f, 0.f, 0.f, 0.f};

  const unsigned char ASEL[6] = {0, 0, 1, 0, 2, 1};   // hh,hl,lh,hl2,l2h,ll
  const unsigned char BSEL[6] = {0, 1, 0, 2, 0, 1};

  const int nks = npass * 16;
  for (int ks = 0; ks < nks; ++ks) {
    const int pass = ks >> 4, kk = ks & 15;
    const u16* A0 = XP + (size_t)ASEL[pass] * xPlaneStride;
    const u16* B0 = WP + ((size_t)BSEL[pass] << 18);
#pragma unroll
    for (int j = 0; j < 2; ++j) {
      const char* ga = (const char*)(A0 + (size_t)(bm + j * 64 + sRow) * 512 + kk * 32) + sColB;
      const char* gb = (const char*)(B0 + (size_t)(bn + j * 64 + sRow) * 512 + kk * 32) + sColB;
      char* la = (char*)As + (j * 256 + wv * 64) * 16;
      char* lb = (char*)Bs + (j * 256 + wv * 64) * 16;
      __builtin_amdgcn_global_load_lds((const __attribute__((address_space(1))) void*)ga,
                                       (__attribute__((address_space(3))) void*)la, 16, 0, 0);
      __builtin_amdgcn_global_load_lds((const __attribute__((address_space(1))) void*)gb,
                                       (__attribute__((address_space(3))) void*)lb, 16, 0, 0);
    }
    __syncthreads();
    short8 af[4], bf[4];
#pragma unroll
    for (int mi = 0; mi < 4; ++mi)
      af[mi] = *(const short8*)&As[(wm + mi * 16 + fr) * 32 + quad * 8];
#pragma unroll
    for (int ni = 0; ni < 4; ++ni)
      bf[ni] = *(const short8*)&Bs[(wn + ni * 16 + fr) * 32 + quad * 8];
#pragma unroll
    for (int mi = 0; mi < 4; ++mi)
#pragma unroll
      for (int ni = 0; ni < 4; ++ni)
        acc[mi * 4 + ni] = __builtin_amdgcn_mfma_f32_16x16x32_bf16(
            af[mi], bf[ni], acc[mi * 4 + ni], 0, 0, 0);
    __syncthreads();
  }
#pragma unroll
  for (int mi = 0; mi < 4; ++mi)
#pragma unroll
    for (int ni = 0; ni < 4; ++ni) {
      const f32x4 a = acc[mi * 4 + ni];
      float* yp = Y + (size_t)(bm + wm + mi * 16 + quad * 4) * 512 + (bn + wn + ni * 16 + fr);
#pragma unroll
      for (int r = 0; r < 4; ++r) yp[(size_t)r * 512] = a[r];
    }
}

// ================= QK_sample -> M = max - mean per (b,h,q) =================
// One wave per (b,q), all 8 heads at once. XCD swizzle: b = blockIdx & 7 so
// each XCD's L2 mostly serves one batch's K.
__global__ __launch_bounds__(256) void qk_sample_M(
    const float* __restrict__ Q, const float* __restrict__ K,
    const int* __restrict__ sidx, float* __restrict__ M, int S) {
  const int blk = blockIdx.x;
  const int lane = threadIdx.x & 63;
  const int b = blk & 7;
  const int q = ((blk >> 3) << 2) + (threadIdx.x >> 6);
  const int part = lane & 7, h = lane >> 3;

  const float* Qrow = Q + ((size_t)b * LSEQ + q) * D_MODEL + lane * 8;
  float4 qa = ((const float4*)Qrow)[0];
  float4 qb = ((const float4*)Qrow)[1];

  const float* Kb = K + (size_t)b * LSEQ * D_MODEL;
  const int* sp = sidx + (size_t)q * S;

  float mx = -3.4e38f, sum = 0.0f;
  int kk = sp[0];
  const float4* kr = (const float4*)(Kb + (size_t)kk * D_MODEL + lane * 8);
  float4 ka = kr[0], kb4 = kr[1];
  for (int j = 0; j < S; ++j) {
    float4 ca = ka, cb = kb4;
    if (j + 1 < S) {
      int kn = sp[j + 1];
      const float4* krn = (const float4*)(Kb + (size_t)kn * D_MODEL + lane * 8);
      ka = krn[0]; kb4 = krn[1];
    }
    float p = qa.x * ca.x + qa.y * ca.y + qa.z * ca.z + qa.w * ca.w +
              qb.x * cb.x + qb.y * cb.y + qb.z * cb.z + qb.w * cb.w;
    p += __shfl_xor(p, 1, 64);
    p += __shfl_xor(p, 2, 64);
    p += __shfl_xor(p, 4, 64);
    mx = fmaxf(mx, p);
    sum += p;
  }
  if (part == 0) M[((size_t)(b * NHEADS + h)) * LSEQ + q] = mx - sum / (float)S;
}

// ===================== top-U indices per (b,h) =============================
__global__ __launch_bounds__(256) void topk_kernel(
    const float* __restrict__ M, int* __restrict__ Mtop, int U) {
  __shared__ float vals[LSEQ];
  __shared__ float rmax[256];
  __shared__ int ridx[256];
  int bh = blockIdx.x;
  int t = threadIdx.x;
  for (int i = t; i < LSEQ; i += 256) vals[i] = M[(size_t)bh * LSEQ + i];
  __syncthreads();
  for (int it = 0; it < U; ++it) {
    float best = -3.4e38f; int bi = -1;
    for (int i = t; i < LSEQ; i += 256) {
      float v = vals[i];
      if (v > best) { best = v; bi = i; }
    }
    rmax[t] = best; ridx[t] = bi;
    __syncthreads();
    for (int s = 128; s > 0; s >>= 1) {
      if (t < s) {
        if (rmax[t + s] > rmax[t]) { rmax[t] = rmax[t + s]; ridx[t] = ridx[t + s]; }
      }
      __syncthreads();
    }
    if (t == 0) {
      Mtop[(size_t)bh * U + it] = ridx[0];
      vals[ridx[0]] = -3.4e38f;
    }
    __syncthreads();
  }
}

// ============== flash attention over top-U rows, key-split =================
__global__ __launch_bounds__(256) void attn_flash(
    const float* __restrict__ Q, const float* __restrict__ K,
    const float* __restrict__ V, const int* __restrict__ Mtop,
    float* __restrict__ part_ctx, float* __restrict__ part_m,
    float* __restrict__ part_l, int U, int nsplit, int chunks_per_block) {
  __shared__ float Ks[64 * 64];
  __shared__ float Vs[64 * 64];
  __shared__ float Mw[4][64], Lw[4][64];
  const int bh = blockIdx.y, split = blockIdx.x;
  const int h = bh & (NHEADS - 1), b = bh >> 3;
  const int t = threadIdx.x, w = t >> 6, lane = t & 63;

  int qrow = (lane < U) ? Mtop[(size_t)bh * U + lane] : 0;
  const float4* Qp = (const float4*)(Q + ((size_t)(b * LSEQ) + qrow) * D_MODEL + h * EDIM);
  float4 q4[16], c4[16];
#pragma unroll
  for (int i = 0; i < 16; ++i) q4[i] = Qp[i];
#pragma unroll
  for (int i = 0; i < 16; ++i) c4[i] = make_float4(0.f, 0.f, 0.f, 0.f);
  float m = -1e30f, l = 0.0f;

  const int k_base = split * (chunks_per_block * 64);
  for (int c = 0; c < chunks_per_block; ++c) {
    const int k0 = k_base + c * 64;
    const float4* Kg = (const float4*)(K + ((size_t)(b * LSEQ) + k0) * D_MODEL + h * EDIM);
    const float4* Vg = (const float4*)(V + ((size_t)(b * LSEQ) + k0) * D_MODEL + h * EDIM);
#pragma unroll
    for (int i = 0; i < 4; ++i) {
      int f = t + i * 256;
      int row = f >> 4, col4 = f & 15;
      ((float4*)Ks)[f] = Kg[(size_t)row * 128 + col4];
      ((float4*)Vs)[f] = Vg[(size_t)row * 128 + col4];
    }
    __syncthreads();
#pragma unroll 1
    for (int rr = 0; rr < 16; ++rr) {
      const int r = w * 16 + rr;
      const float4* kr = (const float4*)&Ks[r * 64];
      float s = 0.0f;
#pragma unroll
      for (int i = 0; i < 16; ++i) {
        float4 kv = kr[i];
        s += q4[i].x * kv.x + q4[i].y * kv.y + q4[i].z * kv.z + q4[i].w * kv.w;
      }
      s *= 0.125f;
      if (s > m) {
        float f = __expf(m - s);
        l *= f;
#pragma unroll
        for (int i = 0; i < 16; ++i) {
          c4[i].x *= f; c4[i].y *= f; c4[i].z *= f; c4[i].w *= f;
        }
        m = s;
      }
      float p = __expf(s - m);
      l += p;
      const float4* vr = (const float4*)&Vs[r * 64];
#pragma unroll
      for (int i = 0; i < 16; ++i) {
        float4 vv = vr[i];
        c4[i].x += p * vv.x; c4[i].y += p * vv.y;
        c4[i].z += p * vv.z; c4[i].w += p * vv.w;
      }
    }
    __syncthreads();
  }

  Mw[w][lane] = m; Lw[w][lane] = l;
  __syncthreads();
  float Mg = fmaxf(fmaxf(Mw[0][lane], Mw[1][lane]), fmaxf(Mw[2][lane], Mw[3][lane]));
  float Lg = 0.0f;
#pragma unroll
  for (int w2 = 0; w2 < 4; ++w2) Lg += Lw[w2][lane] * __expf(Mw[w2][lane] - Mg);
  float sw = __expf(m - Mg);
  float* acc = Ks;
  for (int w2 = 0; w2 < 4; ++w2) {
    if (w == w2) {
#pragma unroll
      for (int i = 0; i < 16; ++i) {
        int e = i * 4;
        if (w2 == 0) {
          acc[(e + 0) * 64 + lane] = c4[i].x * sw;
          acc[(e + 1) * 64 + lane] = c4[i].y * sw;
          acc[(e + 2) * 64 + lane] = c4[i].z * sw;
          acc[(e + 3) * 64 + lane] = c4[i].w * sw;
        } else {
          acc[(e + 0) * 64 + lane] += c4[i].x * sw;
          acc[(e + 1) * 64 + lane] += c4[i].y * sw;
          acc[(e + 2) * 64 + lane] += c4[i].z * sw;
          acc[(e + 3) * 64 + lane] += c4[i].w * sw;
        }
      }
    }
    __syncthreads();
  }
  if (w == 0 && lane < U) {
    part_m[(size_t)(bh * nsplit + split) * 64 + lane] = Mg;
    part_l[(size_t)(bh * nsplit + split) * 64 + lane] = Lg;
  }
  float* pc = part_ctx + (size_t)(bh * nsplit + split) * 4096;
#pragma unroll
  for (int i = 0; i < 16; ++i) {
    int f = t + i * 256;
    pc[f] = acc[f];
  }
}

// =================== combine key-split flash partials ======================
__global__ __launch_bounds__(256) void attn_combine(
    const float* __restrict__ part_ctx, const float* __restrict__ part_m,
    const float* __restrict__ part_l, float* __restrict__ ctxTop,
    int U, int nsplit) {
  __shared__ float F[16][64];
  const int bh = blockIdx.x;
  const int t = threadIdx.x, lane = t & 63, grp = t >> 6;
  if (grp == 0) {
    float M = -3.4e38f;
    for (int s = 0; s < nsplit; ++s)
      M = fmaxf(M, part_m[(size_t)(bh * nsplit + s) * 64 + lane]);
    float L = 0.0f;
    for (int s = 0; s < nsplit; ++s)
      L += part_l[(size_t)(bh * nsplit + s) * 64 + lane] *
           __expf(part_m[(size_t)(bh * nsplit + s) * 64 + lane] - M);
    float invL = 1.0f / L;
    for (int s = 0; s < nsplit; ++s)
      F[s][lane] = __expf(part_m[(size_t)(bh * nsplit + s) * 64 + lane] - M) * invL;
  }
  __syncthreads();
  for (int ei = 0; ei < 16; ++ei) {
    int e = grp * 16 + ei;
    float acc = 0.0f;
    for (int s = 0; s < nsplit; ++s)
      acc += F[s][lane] * part_ctx[(size_t)(bh * nsplit + s) * 4096 + e * 64 + lane];
    if (lane < U) ctxTop[((size_t)bh * U + lane) * 64 + e] = acc;
  }
}

// ====================== V.mean over keys per (b,h) =========================
__global__ __launch_bounds__(256) void vmean_kernel(
    const float* __restrict__ V, float* __restrict__ Vm) {
  __shared__ float part[4][EDIM];
  int bh = blockIdx.x;
  int h = bh & (NHEADS - 1), b = bh >> 3;
  int t = threadIdx.x;
  int e = t & 63, c = t >> 6;
  float s = 0.0f;
  for (int k = c * (LSEQ / 4); k < (c + 1) * (LSEQ / 4); ++k)
    s += V[((size_t)b * LSEQ + k) * D_MODEL + h * EDIM + e];
  part[c][e] = s;
  __syncthreads();
  if (c == 0)
    Vm[(size_t)bh * EDIM + e] =
        (part[0][e] + part[1][e] + part[2][e] + part[3][e]) * (1.0f / (float)LSEQ);
}

// ============ base_out[b] = concat_h(Vmean[b,h]) @ W_out + b_out ===========
__global__ __launch_bounds__(256) void base_out_kernel(
    const float* __restrict__ Vm, const float* __restrict__ Wout,
    const float* __restrict__ bout, float* __restrict__ base) {
  __shared__ float cb[D_MODEL];
  int b = blockIdx.x;
  int t = threadIdx.x;
  for (int d = t; d < D_MODEL; d += 256) cb[d] = Vm[(size_t)b * D_MODEL + d];
  __syncthreads();
  for (int n = t; n < D_MODEL; n += 256) {
    float s = bout[n];
    for (int d = 0; d < D_MODEL; ++d) s += cb[d] * Wout[(size_t)d * D_MODEL + n];
    base[(size_t)b * D_MODEL + n] = s;
  }
}

// ================== broadcast base row into all output rows ================
__global__ __launch_bounds__(256) void fill_out(
    const float* __restrict__ base, float* __restrict__ out) {
  size_t i = (size_t)blockIdx.x * 256 + threadIdx.x;
  int n4 = (int)(i & 127);
  size_t bq = i >> 7;
  int b = (int)(bq >> 12);
  float4 v = ((const float4*)base)[(size_t)b * 128 + n4];
  ((float4*)out)[i] = v;
}

// ====== add (ctxTop - Vmean) @ W_out[h-slice] into the top rows ============
__global__ __launch_bounds__(256) void delta_out(
    const float* __restrict__ ctxTop, const float* __restrict__ Vm,
    const int* __restrict__ Mtop, const float* __restrict__ Wout,
    float* __restrict__ out, int U) {
  __shared__ float dlt[EDIM];
  int blk = blockIdx.x;
  int u = blk % U, bh = blk / U;
  int h = bh & (NHEADS - 1), b = bh >> 3;
  int q = Mtop[(size_t)bh * U + u];
  int t = threadIdx.x;
  if (t < EDIM)
    dlt[t] = ctxTop[((size_t)bh * U + u) * EDIM + t] - Vm[(size_t)bh * EDIM + t];
  __syncthreads();
  float* orow = out + ((size_t)b * LSEQ + q) * D_MODEL;
  for (int n = t; n < D_MODEL; n += 256) {
    float s = 0.0f;
#pragma unroll
    for (int e = 0; e < EDIM; ++e) s += dlt[e] * Wout[(size_t)(h * EDIM + e) * D_MODEL + n];
    atomicAdd(&orow[n], s);
  }
}

// ===========================================================================
extern "C" void kernel_launch(void* const* d_in, const int* in_sizes, int n_in,
                              void* d_out, int out_size, void* d_ws, size_t ws_size,
                              hipStream_t stream) {
  const float* query  = (const float*)d_in[0];
  const float* key_in = (const float*)d_in[1];
  const float* value  = (const float*)d_in[2];
  const float* W_Q    = (const float*)d_in[3];
  const float* W_K    = (const float*)d_in[4];
  const float* W_V    = (const float*)d_in[5];
  const float* W_out  = (const float*)d_in[6];
  const float* b_out  = (const float*)d_in[7];
  const int*   sidx   = (const int*)d_in[8];
  float* out = (float*)d_out;

  const int S = in_sizes[8] / LSEQ;   // 41
  const int U = S;

  char* ws = (char*)d_ws;
  size_t o = 0;
  float* Qf     = (float*)(ws + o); o += (size_t)BATCH * LSEQ * D_MODEL * 4;
  float* Kf     = (float*)(ws + o); o += (size_t)BATCH * LSEQ * D_MODEL * 4;
  float* Vf     = (float*)(ws + o); o += (size_t)BATCH * LSEQ * D_MODEL * 4;
  int*   Mtop   = (int*)  (ws + o); o += ((size_t)64 * U * 4 + 255) & ~255ULL;
  float* ctxTop = (float*)(ws + o); o += ((size_t)64 * U * EDIM * 4 + 255) & ~255ULL;
  float* Vm     = (float*)(ws + o); o += 16384;
  float* baseO  = (float*)(ws + o); o += 16384;
  u16*   Wpl    = (u16*)  (ws + o); o += (size_t)3 * 786432 * 2;   // 4.5 MB
  size_t unionOff = o;   // X planes / M / flash partials (disjoint lifetimes)

  // adaptive M-chunking so split planes fit
  int nchunk = 2;
  while (nchunk < 16 &&
         unionOff + 3 * ((size_t)(32768 / nchunk) * 512 * 2) > ws_size)
    nchunk <<= 1;
  const int Mchunk = 32768 / nchunk;
  u16* planes = (u16*)(ws + unionOff);
  const int planeStride = Mchunk * 512;

  float* M = (float*)(ws + unionOff);            // 1 MB, after gemms
  int nsplit = 16;
  for (;;) {
    size_t need = unionOff + 2 * ((size_t)64 * nsplit * 64 * 4)
                  + (size_t)64 * nsplit * 4096 * 4;
    if (need <= ws_size || nsplit == 1) break;
    nsplit >>= 1;
  }
  float* part_m   = (float*)(ws + unionOff);
  float* part_l   = part_m + (size_t)64 * nsplit * 64;
  float* part_ctx = part_l + (size_t)64 * nsplit * 64;
  const int chunks_per_block = 64 / nsplit;

  // ---- projections via split-bf16 MFMA ----
  cvt_w<<<dim3(8, 8, 3), 256, 0, stream>>>(W_Q, W_K, W_V, Wpl);
  const float* Xsrc[3] = {query, key_in, value};
  float* Ydst[3] = {Qf, Kf, Vf};
  const int npassArr[3] = {6, 6, 4};   // Q,K fp32-exactness; V 2-term enough
  for (int g = 0; g < 3; ++g) {
    for (int c = 0; c < nchunk; ++c) {
      const float* xc = Xsrc[g] + (size_t)c * Mchunk * 512;
      float* yc = Ydst[g] + (size_t)c * Mchunk * 512;
      cvt_x<<<(Mchunk * 512) / 1024, 256, 0, stream>>>(xc, planes, planeStride);
      gemm_mfma<<<dim3(Mchunk / 128, 4), 256, 0, stream>>>(
          planes, planeStride, Wpl + (size_t)g * 786432, yc, npassArr[g]);
    }
  }

  qk_sample_M<<<(BATCH * LSEQ) / 4, 256, 0, stream>>>(Qf, Kf, sidx, M, S);
  topk_kernel<<<BATCH * NHEADS, 256, 0, stream>>>(M, Mtop, U);
  attn_flash<<<dim3(nsplit, BATCH * NHEADS), 256, 0, stream>>>(
      Qf, Kf, Vf, Mtop, part_ctx, part_m, part_l, U, nsplit, chunks_per_block);
  attn_combine<<<BATCH * NHEADS, 256, 0, stream>>>(
      part_ctx, part_m, part_l, ctxTop, U, nsplit);
  vmean_kernel<<<BATCH * NHEADS, 256, 0, stream>>>(Vf, Vm);
  base_out_kernel<<<BATCH, 256, 0, stream>>>(Vm, W_out, b_out, baseO);
  fill_out<<<(BATCH * LSEQ * (D_MODEL / 4)) / 256, 256, 0, stream>>>(baseO, out);
  delta_out<<<BATCH * NHEADS * U, 256, 0, stream>>>(ctxTop, Vm, Mtop, W_out, out, U);
}

// Round 5
// 1180.280 us; speedup vs baseline: 3.0337x; 1.1577x over previous
//
#include <hip/hip_runtime.h>
#include <cstdint>
#include <cstddef>

#define D_MODEL 512
#define NHEADS  8
#define EDIM    64
#define BATCH   8
#define LSEQ    4096

typedef unsigned short u16;
typedef __attribute__((ext_vector_type(8))) short short8;
typedef __attribute__((ext_vector_type(4))) float f32x4;

// ===================== fp32 -> 2-term bf16 split ===========================
__device__ __forceinline__ u16 bf16_rne(float x) {
  unsigned int u = __float_as_uint(x);
  u += 0x7FFFu + ((u >> 16) & 1u);
  return (u16)(u >> 16);
}
__device__ __forceinline__ void split2(float x, u16& h, u16& l) {
  h = bf16_rne(x);
  float hf = __uint_as_float((unsigned int)h << 16);
  l = bf16_rne(x - hf);
}

// X (fp32, Mchunk x 512) -> 2 bf16 planes (h, l)
__global__ __launch_bounds__(256) void cvt_x(
    const float* __restrict__ X, u16* __restrict__ P, int planeStride) {
  size_t i = ((size_t)blockIdx.x * 256 + threadIdx.x) * 4;
  float4 x = *(const float4*)(X + i);
  ushort4 h, l;
  split2(x.x, h.x, l.x);
  split2(x.y, h.y, l.y);
  split2(x.z, h.z, l.z);
  split2(x.w, h.w, l.w);
  *(ushort4*)(P + i) = h;
  *(ushort4*)(P + planeStride + i) = l;
}

// W (512x512 fp32, k-major) -> transposed planes WT[n][k] (h,l), 3 weights
__global__ __launch_bounds__(256) void cvt_w(
    const float* __restrict__ W0, const float* __restrict__ W1,
    const float* __restrict__ W2, u16* __restrict__ out) {
  const float* W = (blockIdx.z == 0) ? W0 : ((blockIdx.z == 1) ? W1 : W2);
  u16* P = out + (size_t)blockIdx.z * 524288;       // 2 planes of 262144
  __shared__ float tile[64][65];
  const int k0 = blockIdx.x * 64, n0 = blockIdx.y * 64;
  const int t = threadIdx.x;
  const int tr = t >> 4, tc = (t & 15) * 4;
#pragma unroll
  for (int j = 0; j < 4; ++j) {
    int kr = tr + j * 16;
    float4 v = *(const float4*)(W + (size_t)(k0 + kr) * 512 + n0 + tc);
    tile[kr][tc + 0] = v.x; tile[kr][tc + 1] = v.y;
    tile[kr][tc + 2] = v.z; tile[kr][tc + 3] = v.w;
  }
  __syncthreads();
#pragma unroll
  for (int j = 0; j < 4; ++j) {
    int nr = tr + j * 16;
    ushort4 h, l;
    split2(tile[tc + 0][nr], h.x, l.x);
    split2(tile[tc + 1][nr], h.y, l.y);
    split2(tile[tc + 2][nr], h.z, l.z);
    split2(tile[tc + 3][nr], h.w, l.w);
    size_t off = (size_t)(n0 + nr) * 512 + k0 + tc;
    *(ushort4*)(P + off) = h;
    *(ushort4*)(P + 262144 + off) = l;
  }
}

// ========== split-bf16 MFMA GEMM: Y = X @ W ================================
// 128x128 tile, BK=32, 4 waves. 3 passes of 16 k-steps: XhWh + XhWl + XlWh
// (drops XlWl ~ 2^-18 rel — safe for top-k and output threshold).
__global__ __launch_bounds__(256) void gemm_mfma(
    const u16* __restrict__ XP, int xPlaneStride,
    const u16* __restrict__ WP, float* __restrict__ Y, int npass) {
  __shared__ u16 As[128 * 32];
  __shared__ u16 Bs[128 * 32];
  const int tid = threadIdx.x;
  const int lane = tid & 63, wv = tid >> 6;
  const int wm = (wv & 1) * 64, wn = (wv >> 1) * 64;
  const int bm = blockIdx.x * 128, bn = blockIdx.y * 128;
  const int fr = lane & 15, quad = lane >> 4;
  const int sRow = tid >> 2, sColB = (tid & 3) * 16;

  f32x4 acc[16];
#pragma unroll
  for (int i = 0; i < 16; ++i) acc[i] = (f32x4){0.f, 0.f, 0.f, 0.f};

  const unsigned char ASEL[3] = {0, 0, 1};   // hh, hl, lh
  const unsigned char BSEL[3] = {0, 1, 0};

  const int nks = npass * 16;
  for (int ks = 0; ks < nks; ++ks) {
    const int pass = ks >> 4, kk = ks & 15;
    const u16* A0 = XP + (size_t)ASEL[pass] * xPlaneStride;
    const u16* B0 = WP + ((size_t)BSEL[pass] << 18);
#pragma unroll
    for (int j = 0; j < 2; ++j) {
      const char* ga = (const char*)(A0 + (size_t)(bm + j * 64 + sRow) * 512 + kk * 32) + sColB;
      const char* gb = (const char*)(B0 + (size_t)(bn + j * 64 + sRow) * 512 + kk * 32) + sColB;
      char* la = (char*)As + (j * 256 + wv * 64) * 16;
      char* lb = (char*)Bs + (j * 256 + wv * 64) * 16;
      __builtin_amdgcn_global_load_lds((const __attribute__((address_space(1))) void*)ga,
                                       (__attribute__((address_space(3))) void*)la, 16, 0, 0);
      __builtin_amdgcn_global_load_lds((const __attribute__((address_space(1))) void*)gb,
                                       (__attribute__((address_space(3))) void*)lb, 16, 0, 0);
    }
    __syncthreads();
    short8 af[4], bf[4];
#pragma unroll
    for (int mi = 0; mi < 4; ++mi)
      af[mi] = *(const short8*)&As[(wm + mi * 16 + fr) * 32 + quad * 8];
#pragma unroll
    for (int ni = 0; ni < 4; ++ni)
      bf[ni] = *(const short8*)&Bs[(wn + ni * 16 + fr) * 32 + quad * 8];
#pragma unroll
    for (int mi = 0; mi < 4; ++mi)
#pragma unroll
      for (int ni = 0; ni < 4; ++ni)
        acc[mi * 4 + ni] = __builtin_amdgcn_mfma_f32_16x16x32_bf16(
            af[mi], bf[ni], acc[mi * 4 + ni], 0, 0, 0);
    __syncthreads();
  }
#pragma unroll
  for (int mi = 0; mi < 4; ++mi)
#pragma unroll
    for (int ni = 0; ni < 4; ++ni) {
      const f32x4 a = acc[mi * 4 + ni];
      float* yp = Y + (size_t)(bm + wm + mi * 16 + quad * 4) * 512 + (bn + wn + ni * 16 + fr);
#pragma unroll
      for (int r = 0; r < 4; ++r) yp[(size_t)r * 512] = a[r];
    }
}

// ================= QK_sample -> M, half-row per pass =======================
// hg selects heads hg*4..hg*4+3 => K columns [hg*256, hg*256+256).
// Per-batch working set = 4096 rows x 1KB = 4MB = one XCD's L2.
// lane = head(4) x sub(16), each lane owns 4 elems; 4-shuffle reduction.
__global__ __launch_bounds__(256) void qk_sample_half(
    const float* __restrict__ Q, const float* __restrict__ K,
    const int* __restrict__ sidx, float* __restrict__ M, int S, int hg) {
  const int blk = blockIdx.x;
  const int lane = threadIdx.x & 63;
  const int b = blk & 7;                      // XCD swizzle: batch <-> XCD
  const int q = ((blk >> 3) << 2) + (threadIdx.x >> 6);
  const int sub = lane & 15, hl = lane >> 4;
  const int h = hg * 4 + hl;
  const int col = hg * 256 + hl * 64 + sub * 4;

  float4 qv = *(const float4*)(Q + ((size_t)b * LSEQ + q) * D_MODEL + col);
  const float* Kb = K + (size_t)b * LSEQ * D_MODEL + col;
  const int* sp = sidx + (size_t)q * S;

  float mx = -3.4e38f, sum = 0.0f;
  float4 ka = *(const float4*)(Kb + (size_t)sp[0] * D_MODEL);
  for (int j = 0; j < S; ++j) {
    float4 ca = ka;
    if (j + 1 < S)
      ka = *(const float4*)(Kb + (size_t)sp[j + 1] * D_MODEL);
    float p = qv.x * ca.x + qv.y * ca.y + qv.z * ca.z + qv.w * ca.w;
    p += __shfl_xor(p, 1, 64);
    p += __shfl_xor(p, 2, 64);
    p += __shfl_xor(p, 4, 64);
    p += __shfl_xor(p, 8, 64);   // 16-lane group done
    mx = fmaxf(mx, p);
    sum += p;
  }
  if (sub == 0) M[((size_t)(b * NHEADS + h)) * LSEQ + q] = mx - sum / (float)S;
}

// ===================== top-U indices per (b,h) =============================
__global__ __launch_bounds__(256) void topk_kernel(
    const float* __restrict__ M, int* __restrict__ Mtop, int U) {
  __shared__ float vals[LSEQ];
  __shared__ float rmax[256];
  __shared__ int ridx[256];
  int bh = blockIdx.x;
  int t = threadIdx.x;
  for (int i = t; i < LSEQ; i += 256) vals[i] = M[(size_t)bh * LSEQ + i];
  __syncthreads();
  for (int it = 0; it < U; ++it) {
    float best = -3.4e38f; int bi = -1;
    for (int i = t; i < LSEQ; i += 256) {
      float v = vals[i];
      if (v > best) { best = v; bi = i; }
    }
    rmax[t] = best; ridx[t] = bi;
    __syncthreads();
    for (int s = 128; s > 0; s >>= 1) {
      if (t < s) {
        if (rmax[t + s] > rmax[t]) { rmax[t] = rmax[t + s]; ridx[t] = ridx[t + s]; }
      }
      __syncthreads();
    }
    if (t == 0) {
      Mtop[(size_t)bh * U + it] = ridx[0];
      vals[ridx[0]] = -3.4e38f;
    }
    __syncthreads();
  }
}

// ============== flash attention over top-U rows, key-split =================
__global__ __launch_bounds__(256) void attn_flash(
    const float* __restrict__ Q, const float* __restrict__ K,
    const float* __restrict__ V, const int* __restrict__ Mtop,
    float* __restrict__ part_ctx, float* __restrict__ part_m,
    float* __restrict__ part_l, int U, int nsplit, int chunks_per_block) {
  __shared__ float Ks[64 * 64];
  __shared__ float Vs[64 * 64];
  __shared__ float Mw[4][64], Lw[4][64];
  const int bh = blockIdx.y, split = blockIdx.x;
  const int h = bh & (NHEADS - 1), b = bh >> 3;
  const int t = threadIdx.x, w = t >> 6, lane = t & 63;

  int qrow = (lane < U) ? Mtop[(size_t)bh * U + lane] : 0;
  const float4* Qp = (const float4*)(Q + ((size_t)(b * LSEQ) + qrow) * D_MODEL + h * EDIM);
  float4 q4[16], c4[16];
#pragma unroll
  for (int i = 0; i < 16; ++i) q4[i] = Qp[i];
#pragma unroll
  for (int i = 0; i < 16; ++i) c4[i] = make_float4(0.f, 0.f, 0.f, 0.f);
  float m = -1e30f, l = 0.0f;

  const int k_base = split * (chunks_per_block * 64);
  for (int c = 0; c < chunks_per_block; ++c) {
    const int k0 = k_base + c * 64;
    const float4* Kg = (const float4*)(K + ((size_t)(b * LSEQ) + k0) * D_MODEL + h * EDIM);
    const float4* Vg = (const float4*)(V + ((size_t)(b * LSEQ) + k0) * D_MODEL + h * EDIM);
#pragma unroll
    for (int i = 0; i < 4; ++i) {
      int f = t + i * 256;
      int row = f >> 4, col4 = f & 15;
      ((float4*)Ks)[f] = Kg[(size_t)row * 128 + col4];
      ((float4*)Vs)[f] = Vg[(size_t)row * 128 + col4];
    }
    __syncthreads();
#pragma unroll 1
    for (int rr = 0; rr < 16; ++rr) {
      const int r = w * 16 + rr;
      const float4* kr = (const float4*)&Ks[r * 64];
      float s = 0.0f;
#pragma unroll
      for (int i = 0; i < 16; ++i) {
        float4 kv = kr[i];
        s += q4[i].x * kv.x + q4[i].y * kv.y + q4[i].z * kv.z + q4[i].w * kv.w;
      }
      s *= 0.125f;
      if (s > m) {
        float f = __expf(m - s);
        l *= f;
#pragma unroll
        for (int i = 0; i < 16; ++i) {
          c4[i].x *= f; c4[i].y *= f; c4[i].z *= f; c4[i].w *= f;
        }
        m = s;
      }
      float p = __expf(s - m);
      l += p;
      const float4* vr = (const float4*)&Vs[r * 64];
#pragma unroll
      for (int i = 0; i < 16; ++i) {
        float4 vv = vr[i];
        c4[i].x += p * vv.x; c4[i].y += p * vv.y;
        c4[i].z += p * vv.z; c4[i].w += p * vv.w;
      }
    }
    __syncthreads();
  }

  Mw[w][lane] = m; Lw[w][lane] = l;
  __syncthreads();
  float Mg = fmaxf(fmaxf(Mw[0][lane], Mw[1][lane]), fmaxf(Mw[2][lane], Mw[3][lane]));
  float Lg = 0.0f;
#pragma unroll
  for (int w2 = 0; w2 < 4; ++w2) Lg += Lw[w2][lane] * __expf(Mw[w2][lane] - Mg);
  float sw = __expf(m - Mg);
  float* acc = Ks;
  for (int w2 = 0; w2 < 4; ++w2) {
    if (w == w2) {
#pragma unroll
      for (int i = 0; i < 16; ++i) {
        int e = i * 4;
        if (w2 == 0) {
          acc[(e + 0) * 64 + lane] = c4[i].x * sw;
          acc[(e + 1) * 64 + lane] = c4[i].y * sw;
          acc[(e + 2) * 64 + lane] = c4[i].z * sw;
          acc[(e + 3) * 64 + lane] = c4[i].w * sw;
        } else {
          acc[(e + 0) * 64 + lane] += c4[i].x * sw;
          acc[(e + 1) * 64 + lane] += c4[i].y * sw;
          acc[(e + 2) * 64 + lane] += c4[i].z * sw;
          acc[(e + 3) * 64 + lane] += c4[i].w * sw;
        }
      }
    }
    __syncthreads();
  }
  if (w == 0 && lane < U) {
    part_m[(size_t)(bh * nsplit + split) * 64 + lane] = Mg;
    part_l[(size_t)(bh * nsplit + split) * 64 + lane] = Lg;
  }
  float* pc = part_ctx + (size_t)(bh * nsplit + split) * 4096;
#pragma unroll
  for (int i = 0; i < 16; ++i) {
    int f = t + i * 256;
    pc[f] = acc[f];
  }
}

// =================== combine key-split flash partials ======================
__global__ __launch_bounds__(256) void attn_combine(
    const float* __restrict__ part_ctx, const float* __restrict__ part_m,
    const float* __restrict__ part_l, float* __restrict__ ctxTop,
    int U, int nsplit) {
  __shared__ float F[16][64];
  const int bh = blockIdx.x;
  const int t = threadIdx.x, lane = t & 63, grp = t >> 6;
  if (grp == 0) {
    float M = -3.4e38f;
    for (int s = 0; s < nsplit; ++s)
      M = fmaxf(M, part_m[(size_t)(bh * nsplit + s) * 64 + lane]);
    float L = 0.0f;
    for (int s = 0; s < nsplit; ++s)
      L += part_l[(size_t)(bh * nsplit + s) * 64 + lane] *
           __expf(part_m[(size_t)(bh * nsplit + s) * 64 + lane] - M);
    float invL = 1.0f / L;
    for (int s = 0; s < nsplit; ++s)
      F[s][lane] = __expf(part_m[(size_t)(bh * nsplit + s) * 64 + lane] - M) * invL;
  }
  __syncthreads();
  for (int ei = 0; ei < 16; ++ei) {
    int e = grp * 16 + ei;
    float acc = 0.0f;
    for (int s = 0; s < nsplit; ++s)
      acc += F[s][lane] * part_ctx[(size_t)(bh * nsplit + s) * 4096 + e * 64 + lane];
    if (lane < U) ctxTop[((size_t)bh * U + lane) * 64 + e] = acc;
  }
}

// ====================== V.mean over keys per (b,h) =========================
__global__ __launch_bounds__(256) void vmean_kernel(
    const float* __restrict__ V, float* __restrict__ Vm) {
  __shared__ float part[4][EDIM];
  int bh = blockIdx.x;
  int h = bh & (NHEADS - 1), b = bh >> 3;
  int t = threadIdx.x;
  int e = t & 63, c = t >> 6;
  float s = 0.0f;
  for (int k = c * (LSEQ / 4); k < (c + 1) * (LSEQ / 4); ++k)
    s += V[((size_t)b * LSEQ + k) * D_MODEL + h * EDIM + e];
  part[c][e] = s;
  __syncthreads();
  if (c == 0)
    Vm[(size_t)bh * EDIM + e] =
        (part[0][e] + part[1][e] + part[2][e] + part[3][e]) * (1.0f / (float)LSEQ);
}

// ============ base_out[b] = concat_h(Vmean[b,h]) @ W_out + b_out ===========
__global__ __launch_bounds__(256) void base_out_kernel(
    const float* __restrict__ Vm, const float* __restrict__ Wout,
    const float* __restrict__ bout, float* __restrict__ base) {
  __shared__ float cb[D_MODEL];
  int b = blockIdx.x;
  int t = threadIdx.x;
  for (int d = t; d < D_MODEL; d += 256) cb[d] = Vm[(size_t)b * D_MODEL + d];
  __syncthreads();
  for (int n = t; n < D_MODEL; n += 256) {
    float s = bout[n];
    for (int d = 0; d < D_MODEL; ++d) s += cb[d] * Wout[(size_t)d * D_MODEL + n];
    base[(size_t)b * D_MODEL + n] = s;
  }
}

// ================== broadcast base row into all output rows ================
__global__ __launch_bounds__(256) void fill_out(
    const float* __restrict__ base, float* __restrict__ out) {
  size_t i = (size_t)blockIdx.x * 256 + threadIdx.x;
  int n4 = (int)(i & 127);
  size_t bq = i >> 7;
  int b = (int)(bq >> 12);
  float4 v = ((const float4*)base)[(size_t)b * 128 + n4];
  ((float4*)out)[i] = v;
}

// ====== add (ctxTop - Vmean) @ W_out[h-slice] into the top rows ============
__global__ __launch_bounds__(256) void delta_out(
    const float* __restrict__ ctxTop, const float* __restrict__ Vm,
    const int* __restrict__ Mtop, const float* __restrict__ Wout,
    float* __restrict__ out, int U) {
  __shared__ float dlt[EDIM];
  int blk = blockIdx.x;
  int u = blk % U, bh = blk / U;
  int h = bh & (NHEADS - 1), b = bh >> 3;
  int q = Mtop[(size_t)bh * U + u];
  int t = threadIdx.x;
  if (t < EDIM)
    dlt[t] = ctxTop[((size_t)bh * U + u) * EDIM + t] - Vm[(size_t)bh * EDIM + t];
  __syncthreads();
  float* orow = out + ((size_t)b * LSEQ + q) * D_MODEL;
  for (int n = t; n < D_MODEL; n += 256) {
    float s = 0.0f;
#pragma unroll
    for (int e = 0; e < EDIM; ++e) s += dlt[e] * Wout[(size_t)(h * EDIM + e) * D_MODEL + n];
    atomicAdd(&orow[n], s);
  }
}

// ===========================================================================
extern "C" void kernel_launch(void* const* d_in, const int* in_sizes, int n_in,
                              void* d_out, int out_size, void* d_ws, size_t ws_size,
                              hipStream_t stream) {
  const float* query  = (const float*)d_in[0];
  const float* key_in = (const float*)d_in[1];
  const float* value  = (const float*)d_in[2];
  const float* W_Q    = (const float*)d_in[3];
  const float* W_K    = (const float*)d_in[4];
  const float* W_V    = (const float*)d_in[5];
  const float* W_out  = (const float*)d_in[6];
  const float* b_out  = (const float*)d_in[7];
  const int*   sidx   = (const int*)d_in[8];
  float* out = (float*)d_out;

  const int S = in_sizes[8] / LSEQ;   // 41
  const int U = S;

  char* ws = (char*)d_ws;
  size_t o = 0;
  float* Qf     = (float*)(ws + o); o += (size_t)BATCH * LSEQ * D_MODEL * 4;
  float* Kf     = (float*)(ws + o); o += (size_t)BATCH * LSEQ * D_MODEL * 4;
  float* Vf     = (float*)(ws + o); o += (size_t)BATCH * LSEQ * D_MODEL * 4;
  int*   Mtop   = (int*)  (ws + o); o += ((size_t)64 * U * 4 + 255) & ~255ULL;
  float* ctxTop = (float*)(ws + o); o += ((size_t)64 * U * EDIM * 4 + 255) & ~255ULL;
  float* Vm     = (float*)(ws + o); o += 16384;
  float* baseO  = (float*)(ws + o); o += 16384;
  u16*   Wpl    = (u16*)  (ws + o); o += (size_t)3 * 524288 * 2;   // 3 MB
  size_t unionOff = o;   // X planes / M / flash partials (disjoint lifetimes)

  // adaptive M-chunking so the 2 split planes fit
  int nchunk = 1;
  while (nchunk < 16 &&
         unionOff + 2 * ((size_t)(32768 / nchunk) * 512 * 2) > ws_size)
    nchunk <<= 1;
  const int Mchunk = 32768 / nchunk;
  u16* planes = (u16*)(ws + unionOff);
  const int planeStride = Mchunk * 512;

  float* M = (float*)(ws + unionOff);            // 1 MB, after gemms
  int nsplit = 16;
  for (;;) {
    size_t need = unionOff + 2 * ((size_t)64 * nsplit * 64 * 4)
                  + (size_t)64 * nsplit * 4096 * 4;
    if (need <= ws_size || nsplit == 1) break;
    nsplit >>= 1;
  }
  float* part_m   = (float*)(ws + unionOff);
  float* part_l   = part_m + (size_t)64 * nsplit * 64;
  float* part_ctx = part_l + (size_t)64 * nsplit * 64;
  const int chunks_per_block = 64 / nsplit;

  // ---- projections via split-bf16 MFMA (2-term, 3 passes) ----
  cvt_w<<<dim3(8, 8, 3), 256, 0, stream>>>(W_Q, W_K, W_V, Wpl);
  const float* Xsrc[3] = {query, key_in, value};
  float* Ydst[3] = {Qf, Kf, Vf};
  for (int g = 0; g < 3; ++g) {
    for (int c = 0; c < nchunk; ++c) {
      const float* xc = Xsrc[g] + (size_t)c * Mchunk * 512;
      float* yc = Ydst[g] + (size_t)c * Mchunk * 512;
      cvt_x<<<(Mchunk * 512) / 1024, 256, 0, stream>>>(xc, planes, planeStride);
      gemm_mfma<<<dim3(Mchunk / 128, 4), 256, 0, stream>>>(
          planes, planeStride, Wpl + (size_t)g * 524288, yc, 3);
    }
  }

  qk_sample_half<<<(BATCH * LSEQ) / 4, 256, 0, stream>>>(Qf, Kf, sidx, M, S, 0);
  qk_sample_half<<<(BATCH * LSEQ) / 4, 256, 0, stream>>>(Qf, Kf, sidx, M, S, 1);
  topk_kernel<<<BATCH * NHEADS, 256, 0, stream>>>(M, Mtop, U);
  attn_flash<<<dim3(nsplit, BATCH * NHEADS), 256, 0, stream>>>(
      Qf, Kf, Vf, Mtop, part_ctx, part_m, part_l, U, nsplit, chunks_per_block);
  attn_combine<<<BATCH * NHEADS, 256, 0, stream>>>(
      part_ctx, part_m, part_l, ctxTop, U, nsplit);
  vmean_kernel<<<BATCH * NHEADS, 256, 0, stream>>>(Vf, Vm);
  base_out_kernel<<<BATCH, 256, 0, stream>>>(Vm, W_out, b_out, baseO);
  fill_out<<<(BATCH * LSEQ * (D_MODEL / 4)) / 256, 256, 0, stream>>>(baseO, out);
  delta_out<<<BATCH * NHEADS * U, 256, 0, stream>>>(ctxTop, Vm, Mtop, W_out, out, U);
}